// Round 2
// baseline (283.462 us; speedup 1.0000x reference)
//
#include <hip/hip_runtime.h>
#include <math.h>

// NonLocalBlock2D, fully reassociated:
//   theta = theta_w @ x[b] + theta_b                  [B,128,4096]
//   gp    = maxpool2(g_w   @ y[b] + g_b)              [B,128,1024]
//   pp    = maxpool2(phi_w @ y[b] + phi_b)            [B,128,1024]
//   MT[j,i] = sum_n gp[j,n]*pp[i,n]   (= M[i,j])      [B,128,128]  (K-split partials)
//   P[c,i]  = s_c/Np * sum_j W_w[c,j]*MT[j,i]         [B,256,128]
//   out     = P[b] @ theta[b] + (s_c*W_b+bn_beta) + x [B,256,4096]

namespace {
constexpr int NB = 8;     // batch
constexpr int NC = 256;   // C
constexpr int NI = 128;   // Ci
constexpr int HW = 4096;  // 64*64
constexpr int NP = 1024;  // 32*32
constexpr int NCK = 16;   // K-split chunks for M-partials (64 each)
constexpr float BNEPS = 1e-5f;
}

// ---------------------------------------------------------------------------
// Tiled GEMM: out_tile[128m x 128n] = A[m,:] @ X[b][:,n] (+bias) (+pool/final)
// Block: 256 threads, 8x8 register tile per thread.
// Thread n-cols: {c0..c0+3} U {64+c0..64+c0+3} so the 2x2 maxpool is
// thread-local (an n-tile of 128 pixels == image rows {2r, 2r+1}).
// ---------------------------------------------------------------------------
template<int KTOT, bool POOL, bool FINAL>
__global__ __launch_bounds__(256)
void k_gemm(const float* __restrict__ A, int a_bstride,
            const float* __restrict__ X,
            const float* __restrict__ bias,
            float* __restrict__ out,
            const float* __restrict__ xadd,
            const float* __restrict__ bng,
            const float* __restrict__ bnb)
{
    __shared__ float Ws[32][132];  // k-major A tile, pad->conflict-free/broadcast reads
    __shared__ float Xs[32][128];  // k-major X tile
    const int t = threadIdx.x;
    const int b = blockIdx.z;
    const int mbase = blockIdx.y * 128;
    const int pixbase = blockIdx.x * 128;
    const float* Ab = A + (size_t)b * a_bstride;
    const float* Xb = X + (size_t)b * KTOT * HW;

    float acc[8][8];
#pragma unroll
    for (int i = 0; i < 8; ++i)
#pragma unroll
        for (int j = 0; j < 8; ++j) acc[i][j] = 0.f;

    const int m0 = (t >> 4) << 3;   // 16 m-groups of 8
    const int c0 = (t & 15) << 2;   // 16 n-groups of 4 (+64 twin)

#pragma unroll 1
    for (int kc = 0; kc < KTOT; kc += 32) {
        __syncthreads();
        // stage A chunk transposed: Ws[kk][m] = A[mbase+m][kc+kk]
#pragma unroll
        for (int p = 0; p < 4; ++p) {
            const int m = p * 32 + (t >> 3);
            const int k4 = (t & 7) << 2;
            const float4 v = *(const float4*)&Ab[(size_t)(mbase + m) * KTOT + kc + k4];
            Ws[k4 + 0][m] = v.x; Ws[k4 + 1][m] = v.y;
            Ws[k4 + 2][m] = v.z; Ws[k4 + 3][m] = v.w;
        }
        // stage X chunk: Xs[kk][col] = X[kc+kk][pixbase+col]
#pragma unroll
        for (int p = 0; p < 4; ++p) {
            const int kk = p * 8 + (t >> 5);
            const int col = (t & 31) << 2;
            *(float4*)&Xs[kk][col] =
                *(const float4*)&Xb[(size_t)(kc + kk) * HW + pixbase + col];
        }
        __syncthreads();
#pragma unroll
        for (int kk = 0; kk < 32; ++kk) {
            const float4 a0 = *(const float4*)&Ws[kk][m0];
            const float4 a1 = *(const float4*)&Ws[kk][m0 + 4];
            const float4 b0 = *(const float4*)&Xs[kk][c0];
            const float4 b1 = *(const float4*)&Xs[kk][c0 + 64];
            const float av[8] = {a0.x, a0.y, a0.z, a0.w, a1.x, a1.y, a1.z, a1.w};
            const float bv[8] = {b0.x, b0.y, b0.z, b0.w, b1.x, b1.y, b1.z, b1.w};
#pragma unroll
            for (int i = 0; i < 8; ++i)
#pragma unroll
                for (int j = 0; j < 8; ++j)
                    acc[i][j] = fmaf(av[i], bv[j], acc[i][j]);
        }
    }

    if (POOL) {
        // n-tile == image rows {2r,2r+1}; thread holds cols c0..c0+3 of both rows
        const int pr = blockIdx.x;      // pooled row
        const int pw0 = c0 >> 1;
        float* ob = out + (size_t)b * NI * NP;
#pragma unroll
        for (int i = 0; i < 8; ++i) {
            const int m = m0 + i;
            const float bs = bias[m];
            const float p0 = fmaxf(fmaxf(acc[i][0], acc[i][1]),
                                   fmaxf(acc[i][4], acc[i][5])) + bs;
            const float p1 = fmaxf(fmaxf(acc[i][2], acc[i][3]),
                                   fmaxf(acc[i][6], acc[i][7])) + bs;
            ob[(size_t)m * NP + pr * 32 + pw0]     = p0;
            ob[(size_t)m * NP + pr * 32 + pw0 + 1] = p1;
        }
    } else if (FINAL) {
#pragma unroll
        for (int i = 0; i < 8; ++i) {
            const int c = mbase + m0 + i;
            const float sc = bng[c] / sqrtf(1.f + BNEPS);
            const float beta = sc * bias[c] + bnb[c];   // bias == W_b here
            const size_t base = ((size_t)b * NC + c) * HW + pixbase;
            const float4 x0 = *(const float4*)&xadd[base + c0];
            const float4 x1 = *(const float4*)&xadd[base + c0 + 64];
            float4 o0, o1;
            o0.x = acc[i][0] + beta + x0.x; o0.y = acc[i][1] + beta + x0.y;
            o0.z = acc[i][2] + beta + x0.z; o0.w = acc[i][3] + beta + x0.w;
            o1.x = acc[i][4] + beta + x1.x; o1.y = acc[i][5] + beta + x1.y;
            o1.z = acc[i][6] + beta + x1.z; o1.w = acc[i][7] + beta + x1.w;
            *(float4*)&out[base + c0]      = o0;
            *(float4*)&out[base + c0 + 64] = o1;
        }
    } else {
#pragma unroll
        for (int i = 0; i < 8; ++i) {
            const int m = m0 + i;
            const float bs = bias[m];
            const size_t base = ((size_t)b * NI + m) * HW + pixbase;
            float4 o0, o1;
            o0.x = acc[i][0] + bs; o0.y = acc[i][1] + bs;
            o0.z = acc[i][2] + bs; o0.w = acc[i][3] + bs;
            o1.x = acc[i][4] + bs; o1.y = acc[i][5] + bs;
            o1.z = acc[i][6] + bs; o1.w = acc[i][7] + bs;
            *(float4*)&out[base + c0]      = o0;
            *(float4*)&out[base + c0 + 64] = o1;
        }
    }
}

// ---------------------------------------------------------------------------
// M-partials (NT GEMM): Mpart[ck][b][j][i] = sum_{n in chunk} gp[j,n]*pp[i,n]
// ---------------------------------------------------------------------------
__global__ __launch_bounds__(256)
void k_mpart(const float* __restrict__ G, const float* __restrict__ Ph,
             float* __restrict__ Mpart)
{
    __shared__ float Gs[32][132];
    __shared__ float Ps[32][132];
    const int t = threadIdx.x;
    const int ck = blockIdx.x;
    const int b = blockIdx.y;
    const int nbase = ck * 64;
    const float* Gb = G + (size_t)b * NI * NP;
    const float* Pb = Ph + (size_t)b * NI * NP;

    float acc[8][8];
#pragma unroll
    for (int i = 0; i < 8; ++i)
#pragma unroll
        for (int j = 0; j < 8; ++j) acc[i][j] = 0.f;

    const int j0 = (t >> 4) << 3;
    const int c0 = (t & 15) << 2;

#pragma unroll 1
    for (int kc = 0; kc < 64; kc += 32) {
        __syncthreads();
#pragma unroll
        for (int p = 0; p < 4; ++p) {
            const int r = p * 32 + (t >> 3);
            const int n4 = (t & 7) << 2;
            const float4 g = *(const float4*)&Gb[(size_t)r * NP + nbase + kc + n4];
            Gs[n4 + 0][r] = g.x; Gs[n4 + 1][r] = g.y;
            Gs[n4 + 2][r] = g.z; Gs[n4 + 3][r] = g.w;
            const float4 f = *(const float4*)&Pb[(size_t)r * NP + nbase + kc + n4];
            Ps[n4 + 0][r] = f.x; Ps[n4 + 1][r] = f.y;
            Ps[n4 + 2][r] = f.z; Ps[n4 + 3][r] = f.w;
        }
        __syncthreads();
#pragma unroll
        for (int nn = 0; nn < 32; ++nn) {
            const float4 a0 = *(const float4*)&Gs[nn][j0];
            const float4 a1 = *(const float4*)&Gs[nn][j0 + 4];
            const float4 b0 = *(const float4*)&Ps[nn][c0];
            const float4 b1 = *(const float4*)&Ps[nn][c0 + 64];
            const float av[8] = {a0.x, a0.y, a0.z, a0.w, a1.x, a1.y, a1.z, a1.w};
            const float bv[8] = {b0.x, b0.y, b0.z, b0.w, b1.x, b1.y, b1.z, b1.w};
#pragma unroll
            for (int i = 0; i < 8; ++i)
#pragma unroll
                for (int j = 0; j < 8; ++j)
                    acc[i][j] = fmaf(av[i], bv[j], acc[i][j]);
        }
    }

    float* Mb = Mpart + (size_t)(ck * NB + b) * (NI * NI);
#pragma unroll
    for (int jj = 0; jj < 8; ++jj) {
        float4 o0, o1;
        o0.x = acc[jj][0]; o0.y = acc[jj][1]; o0.z = acc[jj][2]; o0.w = acc[jj][3];
        o1.x = acc[jj][4]; o1.y = acc[jj][5]; o1.z = acc[jj][6]; o1.w = acc[jj][7];
        *(float4*)&Mb[(size_t)(j0 + jj) * NI + c0]      = o0;
        *(float4*)&Mb[(size_t)(j0 + jj) * NI + c0 + 64] = o1;
    }
}

// ---------------------------------------------------------------------------
// Reduce M-partials + P[c,i] = s_c/Np * sum_j W_w[c,j] * MT[j,i]
// Grid: (4 c-groups of 64, 8 batches). W_w rows read from global (L1-resident).
// ---------------------------------------------------------------------------
__global__ __launch_bounds__(256)
void k_reduce_p(const float* __restrict__ Mpart, const float* __restrict__ Wm,
                const float* __restrict__ bng, float* __restrict__ P)
{
    __shared__ float Ms[128][128];
    const int t = threadIdx.x;
    const int cbase = blockIdx.x * 64;
    const int b = blockIdx.y;

#pragma unroll 1
    for (int rep = 0; rep < 16; ++rep) {
        const int flat = rep * 256 + t;
        const int j = flat >> 5;
        const int i4 = (flat & 31) << 2;
        float4 s; s.x = 0.f; s.y = 0.f; s.z = 0.f; s.w = 0.f;
#pragma unroll
        for (int ck = 0; ck < NCK; ++ck) {
            const float4 v = *(const float4*)
                &Mpart[(size_t)(ck * NB + b) * (NI * NI) + (size_t)j * NI + i4];
            s.x += v.x; s.y += v.y; s.z += v.z; s.w += v.w;
        }
        *(float4*)&Ms[j][i4] = s;
    }
    __syncthreads();

    const float inv = 1.f / (float)NP;
    const int i0 = (t & 7) << 4;
#pragma unroll
    for (int pp = 0; pp < 2; ++pp) {
        const int c = cbase + pp * 32 + (t >> 3);
        const float* wrow = Wm + (size_t)c * NI;
        float a[16];
#pragma unroll
        for (int q = 0; q < 16; ++q) a[q] = 0.f;
#pragma unroll 4
        for (int j = 0; j < 128; ++j) {
            const float w = wrow[j];
            const float4 m0v = *(const float4*)&Ms[j][i0];
            const float4 m1v = *(const float4*)&Ms[j][i0 + 4];
            const float4 m2v = *(const float4*)&Ms[j][i0 + 8];
            const float4 m3v = *(const float4*)&Ms[j][i0 + 12];
            a[0]  = fmaf(w, m0v.x, a[0]);  a[1]  = fmaf(w, m0v.y, a[1]);
            a[2]  = fmaf(w, m0v.z, a[2]);  a[3]  = fmaf(w, m0v.w, a[3]);
            a[4]  = fmaf(w, m1v.x, a[4]);  a[5]  = fmaf(w, m1v.y, a[5]);
            a[6]  = fmaf(w, m1v.z, a[6]);  a[7]  = fmaf(w, m1v.w, a[7]);
            a[8]  = fmaf(w, m2v.x, a[8]);  a[9]  = fmaf(w, m2v.y, a[9]);
            a[10] = fmaf(w, m2v.z, a[10]); a[11] = fmaf(w, m2v.w, a[11]);
            a[12] = fmaf(w, m3v.x, a[12]); a[13] = fmaf(w, m3v.y, a[13]);
            a[14] = fmaf(w, m3v.z, a[14]); a[15] = fmaf(w, m3v.w, a[15]);
        }
        const float sc = bng[c] / sqrtf(1.f + BNEPS) * inv;
        float* Pp = P + ((size_t)b * NC + c) * NI + i0;
#pragma unroll
        for (int q = 0; q < 4; ++q) {
            float4 o;
            o.x = a[4 * q] * sc;     o.y = a[4 * q + 1] * sc;
            o.z = a[4 * q + 2] * sc; o.w = a[4 * q + 3] * sc;
            *(float4*)&Pp[4 * q] = o;
        }
    }
}

extern "C" void kernel_launch(void* const* d_in, const int* in_sizes, int n_in,
                              void* d_out, int out_size, void* d_ws, size_t ws_size,
                              hipStream_t stream)
{
    const float* x    = (const float*)d_in[0];
    const float* y    = (const float*)d_in[1];
    const float* g_w  = (const float*)d_in[2];
    const float* g_b  = (const float*)d_in[3];
    const float* th_w = (const float*)d_in[4];
    const float* th_b = (const float*)d_in[5];
    const float* ph_w = (const float*)d_in[6];
    const float* ph_b = (const float*)d_in[7];
    const float* Wm   = (const float*)d_in[8];
    const float* Wb   = (const float*)d_in[9];
    const float* bng  = (const float*)d_in[10];
    const float* bnb  = (const float*)d_in[11];
    float* out = (float*)d_out;
    float* ws  = (float*)d_ws;

    float* theta = ws;                                   // 8*128*4096
    float* gp    = theta + (size_t)NB * NI * HW;         // 8*128*1024
    float* pp    = gp    + (size_t)NB * NI * NP;         // 8*128*1024
    float* mp    = pp    + (size_t)NB * NI * NP;         // 16*8*128*128
    float* P     = mp    + (size_t)NCK * NB * NI * NI;   // 8*256*128

    const dim3 blk(256);
    k_gemm<NC, false, false><<<dim3(32, 1, NB), blk, 0, stream>>>(
        th_w, 0, x, th_b, theta, nullptr, nullptr, nullptr);
    k_gemm<NC, true, false><<<dim3(32, 1, NB), blk, 0, stream>>>(
        g_w, 0, y, g_b, gp, nullptr, nullptr, nullptr);
    k_gemm<NC, true, false><<<dim3(32, 1, NB), blk, 0, stream>>>(
        ph_w, 0, y, ph_b, pp, nullptr, nullptr, nullptr);
    k_mpart<<<dim3(NCK, NB), blk, 0, stream>>>(gp, pp, mp);
    k_reduce_p<<<dim3(4, NB), blk, 0, stream>>>(mp, Wm, bng, P);
    k_gemm<NI, false, true><<<dim3(32, 2, NB), blk, 0, stream>>>(
        P, NC * NI, theta, Wb, out, x, bng, bnb);
}

// Round 3
// 228.847 us; speedup vs baseline: 1.2387x; 1.2387x over previous
//
#include <hip/hip_runtime.h>
#include <math.h>

// NonLocalBlock2D, reassociated + split-bf16 MFMA:
//   thetaT = (theta_w @ x[b] + theta_b)^T            [B,4096,128] f32
//   gp     = maxpool2(g_w   @ y[b] + g_b)            [B,128,1024] f32
//   pp     = maxpool2(phi_w @ y[b] + phi_b)          [B,128,1024] f32
//   MT[j,i] = sum_n gp[j,n]*pp[i,n]                  [B,128,128]  (K-split partials, fp32)
//   P[c,i]  = s_c/Np * sum_j W_w[c,j]*MT[j,i]        [B,256,128]  fp32
//   out     = P[b] @ theta[b] + (s_c*W_b+bn_beta)+x  [B,256,4096]
// GEMMs use v_mfma_f32_16x16x32_bf16 with hi/lo bf16 split (3 products:
// hh + hl + lh), rel err ~2^-16 => fp32-grade accuracy.

namespace {
constexpr int NB = 8;
constexpr int NC = 256;
constexpr int NI = 128;
constexpr int HW = 4096;
constexpr int NP = 1024;
constexpr int NCK = 16;
constexpr float BNEPS = 1e-5f;
}

typedef __bf16 bf16x8 __attribute__((ext_vector_type(8)));
typedef float f32x4 __attribute__((ext_vector_type(4)));

#define MFMA16(a, b, c) __builtin_amdgcn_mfma_f32_16x16x32_bf16((a), (b), (c), 0, 0, 0)

// top-16-bits bf16 with RNE
__device__ __forceinline__ unsigned rne_hi_bits(float f) {
    unsigned b = __float_as_uint(f);
    return (b + 0x7fffu + ((b >> 16) & 1u)) & 0xffff0000u;
}
// split two floats into packed-bf16 hi-plane word and lo-plane word
__device__ __forceinline__ void split2pack(float e0, float e1, unsigned& hp, unsigned& lp) {
    unsigned h0 = rne_hi_bits(e0), h1 = rne_hi_bits(e1);
    float l0 = e0 - __uint_as_float(h0);
    float l1 = e1 - __uint_as_float(h1);
    unsigned g0 = rne_hi_bits(l0), g1 = rne_hi_bits(l1);
    hp = (h0 >> 16) | (h1 & 0xffff0000u);
    lp = (g0 >> 16) | (g1 & 0xffff0000u);
}
// LDS slot swizzle: rows of 64 bf16 (128B) = 8 slots of 16B.
// key uses row bits {0,1,2}^{2,3,4} -> conflict-free for both our
// read pattern (16 consecutive rows) and write pattern (rows stride 4).
__device__ __forceinline__ int swz(int row, int kq) {
    return kq ^ ((row ^ (row >> 2)) & 7);
}

// ---------------------------------------------------------------------------
// theta GEMM: thetaT[b][pix][i] = sum_k theta_w[i][k]*x[b][k][pix] + theta_b[i]
// tile 64i x 128pix, BK=64, 4 waves (2m x 2n).
// ---------------------------------------------------------------------------
__global__ __launch_bounds__(256, 3)
void k_theta(const float* __restrict__ A, const float* __restrict__ abias,
             const float* __restrict__ X, float* __restrict__ outT)
{
    __shared__ unsigned short Ah[64 * 64], Al[64 * 64], Xh[128 * 64], Xl[128 * 64];
    const int t = threadIdx.x;
    const int lane = t & 63;
    const int lq = lane >> 4;
    const int b = blockIdx.z;
    const int ihalf = blockIdx.y;
    const int pixbase = blockIdx.x * 128;
    const int wm = (t >> 7) & 1;
    const int wn = (t >> 6) & 1;
    const float* Xb = X + (size_t)b * NC * HW;

    f32x4 acc[2][4];
#pragma unroll
    for (int i = 0; i < 2; ++i)
#pragma unroll
        for (int j = 0; j < 4; ++j) acc[i][j] = (f32x4)(0.f);

#pragma unroll 1
    for (int kc = 0; kc < NC; kc += 64) {
        // stage A chunk [64 rows][64 k]
        {
            const int k4 = (t & 15) * 4;
            const int kq = k4 >> 3, inner = k4 & 7;
#pragma unroll
            for (int pass = 0; pass < 4; ++pass) {
                const int r = (t >> 4) + pass * 16;
                const float4 v = *(const float4*)&A[(size_t)(ihalf * 64 + r) * NC + kc + k4];
                unsigned hp0, lp0, hp1, lp1;
                split2pack(v.x, v.y, hp0, lp0);
                split2pack(v.z, v.w, hp1, lp1);
                const int idx = r * 64 + swz(r, kq) * 8 + inner;
                *(uint2*)&Ah[idx] = make_uint2(hp0, hp1);
                *(uint2*)&Al[idx] = make_uint2(lp0, lp1);
            }
        }
        // stage X chunk [64 k][128 pix] transposed into [pix][k]
        {
            const int kq = t >> 5;
            const int pix4 = (t & 31) * 4;
            float vv[8][4];
#pragma unroll
            for (int j = 0; j < 8; ++j) {
                const float4 v = *(const float4*)&Xb[(size_t)(kc + kq * 8 + j) * HW + pixbase + pix4];
                vv[j][0] = v.x; vv[j][1] = v.y; vv[j][2] = v.z; vv[j][3] = v.w;
            }
#pragma unroll
            for (int p = 0; p < 4; ++p) {
                unsigned hp[4], lp[4];
#pragma unroll
                for (int j2 = 0; j2 < 4; ++j2)
                    split2pack(vv[2 * j2][p], vv[2 * j2 + 1][p], hp[j2], lp[j2]);
                const int pix = pix4 + p;
                const int idx = pix * 64 + swz(pix, kq) * 8;
                *(uint4*)&Xh[idx] = make_uint4(hp[0], hp[1], hp[2], hp[3]);
                *(uint4*)&Xl[idx] = make_uint4(lp[0], lp[1], lp[2], lp[3]);
            }
        }
        __syncthreads();
#pragma unroll
        for (int s = 0; s < 2; ++s) {
            bf16x8 ah[2], al[2], bh[4], bl[4];
#pragma unroll
            for (int mf = 0; mf < 2; ++mf) {
                const int r = wm * 32 + mf * 16 + (lane & 15);
                const int idx = r * 64 + swz(r, s * 4 + lq) * 8;
                ah[mf] = *(const bf16x8*)&Ah[idx];
                al[mf] = *(const bf16x8*)&Al[idx];
            }
#pragma unroll
            for (int nf = 0; nf < 4; ++nf) {
                const int pix = wn * 64 + nf * 16 + (lane & 15);
                const int idx = pix * 64 + swz(pix, s * 4 + lq) * 8;
                bh[nf] = *(const bf16x8*)&Xh[idx];
                bl[nf] = *(const bf16x8*)&Xl[idx];
            }
#pragma unroll
            for (int mf = 0; mf < 2; ++mf)
#pragma unroll
                for (int nf = 0; nf < 4; ++nf) {
                    acc[mf][nf] = MFMA16(ah[mf], bh[nf], acc[mf][nf]);
                    acc[mf][nf] = MFMA16(ah[mf], bl[nf], acc[mf][nf]);
                    acc[mf][nf] = MFMA16(al[mf], bh[nf], acc[mf][nf]);
                }
        }
        __syncthreads();
    }
#pragma unroll
    for (int mf = 0; mf < 2; ++mf) {
        const int i0 = ihalf * 64 + wm * 32 + mf * 16 + lq * 4;
        const float b0 = abias[i0], b1 = abias[i0 + 1], b2 = abias[i0 + 2], b3 = abias[i0 + 3];
#pragma unroll
        for (int nf = 0; nf < 4; ++nf) {
            const int pix = pixbase + wn * 64 + nf * 16 + (lane & 15);
            float4 o;
            o.x = acc[mf][nf][0] + b0;
            o.y = acc[mf][nf][1] + b1;
            o.z = acc[mf][nf][2] + b2;
            o.w = acc[mf][nf][3] + b3;
            *(float4*)&outT[((size_t)b * HW + pix) * NI + i0] = o;
        }
    }
}

// ---------------------------------------------------------------------------
// fused g+phi GEMM + 2x2 maxpool. tile 64i x 128pix (= image rows {2pr,2pr+1}).
// wave n-frags: {wn*32, wn*32+16, 64+wn*32, 64+wn*32+16} so vertical pool
// pairs are in-wave; horizontal pool via shfl_xor(1).
// ---------------------------------------------------------------------------
__global__ __launch_bounds__(256, 2)
void k_gphi(const float* __restrict__ Ag, const float* __restrict__ gbias,
            const float* __restrict__ Ap, const float* __restrict__ pbias,
            const float* __restrict__ X,
            float* __restrict__ gpout, float* __restrict__ ppout)
{
    __shared__ unsigned short Agh[64 * 64], Agl[64 * 64], Aph[64 * 64], Apl[64 * 64];
    __shared__ unsigned short Xh[128 * 64], Xl[128 * 64];
    const int t = threadIdx.x;
    const int lane = t & 63;
    const int lq = lane >> 4;
    const int b = blockIdx.z;
    const int ihalf = blockIdx.y;
    const int pr = blockIdx.x;          // pooled image row
    const int pixbase = pr * 128;
    const int wm = (t >> 7) & 1;
    const int wn = (t >> 6) & 1;
    const float* Xb = X + (size_t)b * NC * HW;

    f32x4 accg[2][4], accp[2][4];
#pragma unroll
    for (int i = 0; i < 2; ++i)
#pragma unroll
        for (int j = 0; j < 4; ++j) { accg[i][j] = (f32x4)(0.f); accp[i][j] = (f32x4)(0.f); }

    const int nbase[4] = {wn * 32, wn * 32 + 16, 64 + wn * 32, 64 + wn * 32 + 16};

#pragma unroll 1
    for (int kc = 0; kc < NC; kc += 64) {
        {
            const int k4 = (t & 15) * 4;
            const int kq = k4 >> 3, inner = k4 & 7;
#pragma unroll
            for (int pass = 0; pass < 4; ++pass) {
                const int r = (t >> 4) + pass * 16;
                const int idx = r * 64 + swz(r, kq) * 8 + inner;
                float4 v = *(const float4*)&Ag[(size_t)(ihalf * 64 + r) * NC + kc + k4];
                unsigned hp0, lp0, hp1, lp1;
                split2pack(v.x, v.y, hp0, lp0);
                split2pack(v.z, v.w, hp1, lp1);
                *(uint2*)&Agh[idx] = make_uint2(hp0, hp1);
                *(uint2*)&Agl[idx] = make_uint2(lp0, lp1);
                v = *(const float4*)&Ap[(size_t)(ihalf * 64 + r) * NC + kc + k4];
                split2pack(v.x, v.y, hp0, lp0);
                split2pack(v.z, v.w, hp1, lp1);
                *(uint2*)&Aph[idx] = make_uint2(hp0, hp1);
                *(uint2*)&Apl[idx] = make_uint2(lp0, lp1);
            }
        }
        {
            const int kq = t >> 5;
            const int pix4 = (t & 31) * 4;
            float vv[8][4];
#pragma unroll
            for (int j = 0; j < 8; ++j) {
                const float4 v = *(const float4*)&Xb[(size_t)(kc + kq * 8 + j) * HW + pixbase + pix4];
                vv[j][0] = v.x; vv[j][1] = v.y; vv[j][2] = v.z; vv[j][3] = v.w;
            }
#pragma unroll
            for (int p = 0; p < 4; ++p) {
                unsigned hp[4], lp[4];
#pragma unroll
                for (int j2 = 0; j2 < 4; ++j2)
                    split2pack(vv[2 * j2][p], vv[2 * j2 + 1][p], hp[j2], lp[j2]);
                const int pix = pix4 + p;
                const int idx = pix * 64 + swz(pix, kq) * 8;
                *(uint4*)&Xh[idx] = make_uint4(hp[0], hp[1], hp[2], hp[3]);
                *(uint4*)&Xl[idx] = make_uint4(lp[0], lp[1], lp[2], lp[3]);
            }
        }
        __syncthreads();
#pragma unroll
        for (int s = 0; s < 2; ++s) {
            bf16x8 agh[2], agl[2], aph[2], apl[2], bh[4], bl[4];
#pragma unroll
            for (int mf = 0; mf < 2; ++mf) {
                const int r = wm * 32 + mf * 16 + (lane & 15);
                const int idx = r * 64 + swz(r, s * 4 + lq) * 8;
                agh[mf] = *(const bf16x8*)&Agh[idx];
                agl[mf] = *(const bf16x8*)&Agl[idx];
                aph[mf] = *(const bf16x8*)&Aph[idx];
                apl[mf] = *(const bf16x8*)&Apl[idx];
            }
#pragma unroll
            for (int nf = 0; nf < 4; ++nf) {
                const int pix = nbase[nf] + (lane & 15);
                const int idx = pix * 64 + swz(pix, s * 4 + lq) * 8;
                bh[nf] = *(const bf16x8*)&Xh[idx];
                bl[nf] = *(const bf16x8*)&Xl[idx];
            }
#pragma unroll
            for (int mf = 0; mf < 2; ++mf)
#pragma unroll
                for (int nf = 0; nf < 4; ++nf) {
                    accg[mf][nf] = MFMA16(agh[mf], bh[nf], accg[mf][nf]);
                    accg[mf][nf] = MFMA16(agh[mf], bl[nf], accg[mf][nf]);
                    accg[mf][nf] = MFMA16(agl[mf], bh[nf], accg[mf][nf]);
                    accp[mf][nf] = MFMA16(aph[mf], bh[nf], accp[mf][nf]);
                    accp[mf][nf] = MFMA16(aph[mf], bl[nf], accp[mf][nf]);
                    accp[mf][nf] = MFMA16(apl[mf], bh[nf], accp[mf][nf]);
                }
        }
        __syncthreads();
    }
    // pooled epilogue
#pragma unroll
    for (int which = 0; which < 2; ++which) {
        const float* bias = which ? pbias : gbias;
        float* dst = which ? ppout : gpout;
#pragma unroll
        for (int mf = 0; mf < 2; ++mf) {
            const int i0 = ihalf * 64 + wm * 32 + mf * 16 + lq * 4;
#pragma unroll
            for (int nfc = 0; nfc < 2; ++nfc) {
                f32x4 v;
                if (which == 0) {
#pragma unroll
                    for (int r = 0; r < 4; ++r)
                        v[r] = fmaxf(accg[mf][nfc][r], accg[mf][nfc + 2][r]);
                } else {
#pragma unroll
                    for (int r = 0; r < 4; ++r)
                        v[r] = fmaxf(accp[mf][nfc][r], accp[mf][nfc + 2][r]);
                }
                float h[4];
#pragma unroll
                for (int r = 0; r < 4; ++r)
                    h[r] = fmaxf(v[r], __shfl_xor(v[r], 1));
                if ((lane & 1) == 0) {
                    const int pcol = wn * 16 + nfc * 8 + ((lane & 15) >> 1);
#pragma unroll
                    for (int r = 0; r < 4; ++r)
                        dst[((size_t)b * NI + i0 + r) * NP + pr * 32 + pcol] = h[r] + bias[i0 + r];
                }
            }
        }
    }
}

// ---------------------------------------------------------------------------
// M-partials (unchanged fp32): Mpart[ck][b][j][i] = sum_{n in chunk} gp[j,n]*pp[i,n]
// ---------------------------------------------------------------------------
__global__ __launch_bounds__(256)
void k_mpart(const float* __restrict__ G, const float* __restrict__ Ph,
             float* __restrict__ Mpart)
{
    __shared__ float Gs[32][132];
    __shared__ float Ps[32][132];
    const int t = threadIdx.x;
    const int ck = blockIdx.x;
    const int b = blockIdx.y;
    const int nbase = ck * 64;
    const float* Gb = G + (size_t)b * NI * NP;
    const float* Pb = Ph + (size_t)b * NI * NP;

    float acc[8][8];
#pragma unroll
    for (int i = 0; i < 8; ++i)
#pragma unroll
        for (int j = 0; j < 8; ++j) acc[i][j] = 0.f;

    const int j0 = (t >> 4) << 3;
    const int c0 = (t & 15) << 2;

#pragma unroll 1
    for (int kc = 0; kc < 64; kc += 32) {
        __syncthreads();
#pragma unroll
        for (int p = 0; p < 4; ++p) {
            const int r = p * 32 + (t >> 3);
            const int n4 = (t & 7) << 2;
            const float4 g = *(const float4*)&Gb[(size_t)r * NP + nbase + kc + n4];
            Gs[n4 + 0][r] = g.x; Gs[n4 + 1][r] = g.y;
            Gs[n4 + 2][r] = g.z; Gs[n4 + 3][r] = g.w;
            const float4 f = *(const float4*)&Pb[(size_t)r * NP + nbase + kc + n4];
            Ps[n4 + 0][r] = f.x; Ps[n4 + 1][r] = f.y;
            Ps[n4 + 2][r] = f.z; Ps[n4 + 3][r] = f.w;
        }
        __syncthreads();
#pragma unroll
        for (int nn = 0; nn < 32; ++nn) {
            const float4 a0 = *(const float4*)&Gs[nn][j0];
            const float4 a1 = *(const float4*)&Gs[nn][j0 + 4];
            const float4 b0 = *(const float4*)&Ps[nn][c0];
            const float4 b1 = *(const float4*)&Ps[nn][c0 + 64];
            const float av[8] = {a0.x, a0.y, a0.z, a0.w, a1.x, a1.y, a1.z, a1.w};
            const float bv[8] = {b0.x, b0.y, b0.z, b0.w, b1.x, b1.y, b1.z, b1.w};
#pragma unroll
            for (int i = 0; i < 8; ++i)
#pragma unroll
                for (int j = 0; j < 8; ++j)
                    acc[i][j] = fmaf(av[i], bv[j], acc[i][j]);
        }
    }

    float* Mb = Mpart + (size_t)(ck * NB + b) * (NI * NI);
#pragma unroll
    for (int jj = 0; jj < 8; ++jj) {
        float4 o0, o1;
        o0.x = acc[jj][0]; o0.y = acc[jj][1]; o0.z = acc[jj][2]; o0.w = acc[jj][3];
        o1.x = acc[jj][4]; o1.y = acc[jj][5]; o1.z = acc[jj][6]; o1.w = acc[jj][7];
        *(float4*)&Mb[(size_t)(j0 + jj) * NI + c0]      = o0;
        *(float4*)&Mb[(size_t)(j0 + jj) * NI + c0 + 64] = o1;
    }
}

// ---------------------------------------------------------------------------
// Reduce M-partials + P[c,i] = s_c/Np * sum_j W_w[c,j]*MT[j,i]  (unchanged)
// ---------------------------------------------------------------------------
__global__ __launch_bounds__(256)
void k_reduce_p(const float* __restrict__ Mpart, const float* __restrict__ Wm,
                const float* __restrict__ bng, float* __restrict__ P)
{
    __shared__ float Ms[128][128];
    const int t = threadIdx.x;
    const int cbase = blockIdx.x * 64;
    const int b = blockIdx.y;

#pragma unroll 1
    for (int rep = 0; rep < 16; ++rep) {
        const int flat = rep * 256 + t;
        const int j = flat >> 5;
        const int i4 = (flat & 31) << 2;
        float4 s; s.x = 0.f; s.y = 0.f; s.z = 0.f; s.w = 0.f;
#pragma unroll
        for (int ck = 0; ck < NCK; ++ck) {
            const float4 v = *(const float4*)
                &Mpart[(size_t)(ck * NB + b) * (NI * NI) + (size_t)j * NI + i4];
            s.x += v.x; s.y += v.y; s.z += v.z; s.w += v.w;
        }
        *(float4*)&Ms[j][i4] = s;
    }
    __syncthreads();

    const float inv = 1.f / (float)NP;
    const int i0 = (t & 7) << 4;
#pragma unroll
    for (int pp = 0; pp < 2; ++pp) {
        const int c = cbase + pp * 32 + (t >> 3);
        const float* wrow = Wm + (size_t)c * NI;
        float a[16];
#pragma unroll
        for (int q = 0; q < 16; ++q) a[q] = 0.f;
#pragma unroll 4
        for (int j = 0; j < 128; ++j) {
            const float w = wrow[j];
            const float4 m0v = *(const float4*)&Ms[j][i0];
            const float4 m1v = *(const float4*)&Ms[j][i0 + 4];
            const float4 m2v = *(const float4*)&Ms[j][i0 + 8];
            const float4 m3v = *(const float4*)&Ms[j][i0 + 12];
            a[0]  = fmaf(w, m0v.x, a[0]);  a[1]  = fmaf(w, m0v.y, a[1]);
            a[2]  = fmaf(w, m0v.z, a[2]);  a[3]  = fmaf(w, m0v.w, a[3]);
            a[4]  = fmaf(w, m1v.x, a[4]);  a[5]  = fmaf(w, m1v.y, a[5]);
            a[6]  = fmaf(w, m1v.z, a[6]);  a[7]  = fmaf(w, m1v.w, a[7]);
            a[8]  = fmaf(w, m2v.x, a[8]);  a[9]  = fmaf(w, m2v.y, a[9]);
            a[10] = fmaf(w, m2v.z, a[10]); a[11] = fmaf(w, m2v.w, a[11]);
            a[12] = fmaf(w, m3v.x, a[12]); a[13] = fmaf(w, m3v.y, a[13]);
            a[14] = fmaf(w, m3v.z, a[14]); a[15] = fmaf(w, m3v.w, a[15]);
        }
        const float sc = bng[c] / sqrtf(1.f + BNEPS) * inv;
        float* Pp = P + ((size_t)b * NC + c) * NI + i0;
#pragma unroll
        for (int q = 0; q < 4; ++q) {
            float4 o;
            o.x = a[4 * q] * sc;     o.y = a[4 * q + 1] * sc;
            o.z = a[4 * q + 2] * sc; o.w = a[4 * q + 3] * sc;
            *(float4*)&Pp[4 * q] = o;
        }
    }
}

// ---------------------------------------------------------------------------
// final GEMM: out[b][c][pix] = sum_i P[b][c][i]*thetaT[b][pix][i]
//                              + (s_c*W_b[c]+bn_beta[c]) + x[b][c][pix]
// tile 64c x 128pix, BK=64 over i.
// ---------------------------------------------------------------------------
__global__ __launch_bounds__(256, 3)
void k_final(const float* __restrict__ P, const float* __restrict__ TT,
             const float* __restrict__ Wb, const float* __restrict__ bng,
             const float* __restrict__ bnb, const float* __restrict__ xres,
             float* __restrict__ out)
{
    __shared__ unsigned short Ph_[64 * 64], Pl_[64 * 64], Th[128 * 64], Tl[128 * 64];
    const int t = threadIdx.x;
    const int lane = t & 63;
    const int lq = lane >> 4;
    const int b = blockIdx.z;
    const int cbase = blockIdx.y * 64;
    const int pixbase = blockIdx.x * 128;
    const int wm = (t >> 7) & 1;
    const int wn = (t >> 6) & 1;
    const float* Pb = P + (size_t)b * NC * NI;
    const float* Tb = TT + (size_t)b * HW * NI;

    f32x4 acc[2][4];
#pragma unroll
    for (int i = 0; i < 2; ++i)
#pragma unroll
        for (int j = 0; j < 4; ++j) acc[i][j] = (f32x4)(0.f);

#pragma unroll 1
    for (int ic = 0; ic < NI; ic += 64) {
        {
            const int k4 = (t & 15) * 4;
            const int kq = k4 >> 3, inner = k4 & 7;
#pragma unroll
            for (int pass = 0; pass < 4; ++pass) {
                const int r = (t >> 4) + pass * 16;
                const float4 v = *(const float4*)&Pb[(size_t)(cbase + r) * NI + ic + k4];
                unsigned hp0, lp0, hp1, lp1;
                split2pack(v.x, v.y, hp0, lp0);
                split2pack(v.z, v.w, hp1, lp1);
                const int idx = r * 64 + swz(r, kq) * 8 + inner;
                *(uint2*)&Ph_[idx] = make_uint2(hp0, hp1);
                *(uint2*)&Pl_[idx] = make_uint2(lp0, lp1);
            }
        }
        {
            const int i4 = (t & 15) * 4;
            const int kq = i4 >> 3, inner = i4 & 7;
#pragma unroll
            for (int pass = 0; pass < 8; ++pass) {
                const int pix = (t >> 4) + pass * 16;
                const float4 v = *(const float4*)&Tb[(size_t)(pixbase + pix) * NI + ic + i4];
                unsigned hp0, lp0, hp1, lp1;
                split2pack(v.x, v.y, hp0, lp0);
                split2pack(v.z, v.w, hp1, lp1);
                const int idx = pix * 64 + swz(pix, kq) * 8 + inner;
                *(uint2*)&Th[idx] = make_uint2(hp0, hp1);
                *(uint2*)&Tl[idx] = make_uint2(lp0, lp1);
            }
        }
        __syncthreads();
#pragma unroll
        for (int s = 0; s < 2; ++s) {
            bf16x8 ah[2], al[2], bh[4], bl[4];
#pragma unroll
            for (int mf = 0; mf < 2; ++mf) {
                const int r = wm * 32 + mf * 16 + (lane & 15);
                const int idx = r * 64 + swz(r, s * 4 + lq) * 8;
                ah[mf] = *(const bf16x8*)&Ph_[idx];
                al[mf] = *(const bf16x8*)&Pl_[idx];
            }
#pragma unroll
            for (int nf = 0; nf < 4; ++nf) {
                const int pix = wn * 64 + nf * 16 + (lane & 15);
                const int idx = pix * 64 + swz(pix, s * 4 + lq) * 8;
                bh[nf] = *(const bf16x8*)&Th[idx];
                bl[nf] = *(const bf16x8*)&Tl[idx];
            }
#pragma unroll
            for (int mf = 0; mf < 2; ++mf)
#pragma unroll
                for (int nf = 0; nf < 4; ++nf) {
                    acc[mf][nf] = MFMA16(ah[mf], bh[nf], acc[mf][nf]);
                    acc[mf][nf] = MFMA16(ah[mf], bl[nf], acc[mf][nf]);
                    acc[mf][nf] = MFMA16(al[mf], bh[nf], acc[mf][nf]);
                }
        }
        __syncthreads();
    }
    const float rs = rsqrtf(1.f + BNEPS);
#pragma unroll
    for (int mf = 0; mf < 2; ++mf) {
        const int c0 = cbase + wm * 32 + mf * 16 + lq * 4;
        float beta[4];
#pragma unroll
        for (int r = 0; r < 4; ++r) {
            const float scv = bng[c0 + r] * rs;
            beta[r] = scv * Wb[c0 + r] + bnb[c0 + r];
        }
#pragma unroll
        for (int nf = 0; nf < 4; ++nf) {
            const int pix = pixbase + wn * 64 + nf * 16 + (lane & 15);
#pragma unroll
            for (int r = 0; r < 4; ++r) {
                const size_t o = ((size_t)b * NC + c0 + r) * HW + pix;
                out[o] = acc[mf][nf][r] + beta[r] + xres[o];
            }
        }
    }
}

extern "C" void kernel_launch(void* const* d_in, const int* in_sizes, int n_in,
                              void* d_out, int out_size, void* d_ws, size_t ws_size,
                              hipStream_t stream)
{
    const float* x    = (const float*)d_in[0];
    const float* y    = (const float*)d_in[1];
    const float* g_w  = (const float*)d_in[2];
    const float* g_b  = (const float*)d_in[3];
    const float* th_w = (const float*)d_in[4];
    const float* th_b = (const float*)d_in[5];
    const float* ph_w = (const float*)d_in[6];
    const float* ph_b = (const float*)d_in[7];
    const float* Wm   = (const float*)d_in[8];
    const float* Wb   = (const float*)d_in[9];
    const float* bng  = (const float*)d_in[10];
    const float* bnb  = (const float*)d_in[11];
    float* out = (float*)d_out;
    float* ws  = (float*)d_ws;

    float* thetaT = ws;                                    // 8*4096*128
    float* gp     = thetaT + (size_t)NB * HW * NI;         // 8*128*1024
    float* pp     = gp     + (size_t)NB * NI * NP;         // 8*128*1024
    float* mp     = pp     + (size_t)NB * NI * NP;         // 16*8*128*128
    float* P      = mp     + (size_t)NCK * NB * NI * NI;   // 8*256*128

    const dim3 blk(256);
    k_theta<<<dim3(32, 2, NB), blk, 0, stream>>>(th_w, th_b, x, thetaT);
    k_gphi<<<dim3(32, 2, NB), blk, 0, stream>>>(g_w, g_b, ph_w, ph_b, y, gp, pp);
    k_mpart<<<dim3(NCK, NB), blk, 0, stream>>>(gp, pp, mp);
    k_reduce_p<<<dim3(4, NB), blk, 0, stream>>>(mp, Wm, bng, P);
    k_final<<<dim3(32, 4, NB), blk, 0, stream>>>(P, thetaT, Wb, bng, bnb, x, out);
}

// Round 4
// 215.130 us; speedup vs baseline: 1.3176x; 1.0638x over previous
//
#include <hip/hip_runtime.h>
#include <math.h>

// NonLocalBlock2D, reassociated + split-bf16 MFMA, pipelined:
//   thetaT(hi/lo bf16 planes) = (theta_w @ x[b] + theta_b)^T   [B,2,4096,64]
//   gp  = maxpool2(g_w   @ y[b] + g_b)            [B,128,1024] f32
//   pp  = maxpool2(phi_w @ y[b] + phi_b)          [B,128,1024] f32
//   mp[ck] partial:  sum_{n in ck} gp[j,n]*pp[i,n]   (32 chunks of 32)
//   M[b][j][i] = sum_ck mp[ck]                    [B,128,128]
//   P[c,i]  = s_c/Np * sum_j W_w[c,j]*M[j,i]      [B,256,128]
//   out     = P[b] @ theta[b] + (s_c*W_b+bn_beta)+x  [B,256,4096]
// GEMMs: v_mfma_f32_16x16x32_bf16, hi/lo split (hh+hl+lh), rel err ~2^-16.

namespace {
constexpr int NB = 8;
constexpr int NC = 256;
constexpr int NI = 128;
constexpr int HW = 4096;
constexpr int NP = 1024;
constexpr int NCK = 32;   // K-split chunks for M-partials (32 each)
constexpr float BNEPS = 1e-5f;
}

typedef __bf16 bf16x8 __attribute__((ext_vector_type(8)));
typedef float f32x4 __attribute__((ext_vector_type(4)));

#define MFMA16(a, b, c) __builtin_amdgcn_mfma_f32_16x16x32_bf16((a), (b), (c), 0, 0, 0)

__device__ __forceinline__ unsigned rne_hi_bits(float f) {
    unsigned b = __float_as_uint(f);
    return (b + 0x7fffu + ((b >> 16) & 1u)) & 0xffff0000u;
}
__device__ __forceinline__ void split2pack(float e0, float e1, unsigned& hp, unsigned& lp) {
    unsigned h0 = rne_hi_bits(e0), h1 = rne_hi_bits(e1);
    float l0 = e0 - __uint_as_float(h0);
    float l1 = e1 - __uint_as_float(h1);
    unsigned g0 = rne_hi_bits(l0), g1 = rne_hi_bits(l1);
    hp = (h0 >> 16) | (h1 & 0xffff0000u);
    lp = (g0 >> 16) | (g1 & 0xffff0000u);
}
// LDS slot swizzle: rows of 64 bf16 (128B) = 8 slots of 16B.
__device__ __forceinline__ int swz(int row, int kq) {
    return kq ^ ((row ^ (row >> 2)) & 7);
}

// ---------------------------------------------------------------------------
// theta GEMM -> split bf16 planes: outH/outL[b][half][pix][64]
// tile 64i x 128pix, BK=64, reg-prefetch pipeline.
// ---------------------------------------------------------------------------
__global__ __launch_bounds__(256, 3)
void k_theta(const float* __restrict__ A, const float* __restrict__ abias,
             const float* __restrict__ X,
             unsigned short* __restrict__ outH, unsigned short* __restrict__ outL)
{
    __shared__ unsigned short Ah[64 * 64], Al[64 * 64], Xh[128 * 64], Xl[128 * 64];
    const int t = threadIdx.x;
    const int lane = t & 63;
    const int lq = lane >> 4;
    const int b = blockIdx.z;
    const int ihalf = blockIdx.y;
    const int pixbase = blockIdx.x * 128;
    const int wm = (t >> 7) & 1;
    const int wn = (t >> 6) & 1;
    const float* Xb = X + (size_t)b * NC * HW;

    const int k4 = (t & 15) * 4;          // A staging col
    const int kqa = k4 >> 3, ina = k4 & 7;
    const int kqx = t >> 5;               // X staging k-quad
    const int pix4 = (t & 31) * 4;

    f32x4 acc[2][4];
#pragma unroll
    for (int i = 0; i < 2; ++i)
#pragma unroll
        for (int j = 0; j < 4; ++j) acc[i][j] = (f32x4)(0.f);

    float4 pA[4];
    float pXe[8][4];
#pragma unroll
    for (int p = 0; p < 4; ++p)
        pA[p] = *(const float4*)&A[(size_t)(ihalf * 64 + (t >> 4) + p * 16) * NC + k4];
#pragma unroll
    for (int j = 0; j < 8; ++j)
        *(float4*)&pXe[j][0] = *(const float4*)&Xb[(size_t)(kqx * 8 + j) * HW + pixbase + pix4];

#pragma unroll 1
    for (int kc = 0; kc < NC; kc += 64) {
        // ---- stage phase (uses prefetched regs) ----
#pragma unroll
        for (int p = 0; p < 4; ++p) {
            const int r = (t >> 4) + p * 16;
            unsigned hp0, lp0, hp1, lp1;
            split2pack(pA[p].x, pA[p].y, hp0, lp0);
            split2pack(pA[p].z, pA[p].w, hp1, lp1);
            const int idx = r * 64 + swz(r, kqa) * 8 + ina;
            *(uint2*)&Ah[idx] = make_uint2(hp0, hp1);
            *(uint2*)&Al[idx] = make_uint2(lp0, lp1);
        }
#pragma unroll
        for (int p = 0; p < 4; ++p) {
            unsigned hp[4], lp[4];
#pragma unroll
            for (int j2 = 0; j2 < 4; ++j2)
                split2pack(pXe[2 * j2][p], pXe[2 * j2 + 1][p], hp[j2], lp[j2]);
            const int pix = pix4 + p;
            const int idx = pix * 64 + swz(pix, kqx) * 8;
            *(uint4*)&Xh[idx] = make_uint4(hp[0], hp[1], hp[2], hp[3]);
            *(uint4*)&Xl[idx] = make_uint4(lp[0], lp[1], lp[2], lp[3]);
        }
        __syncthreads();
        // ---- prefetch next chunk (overlaps with compute below) ----
        if (kc + 64 < NC) {
#pragma unroll
            for (int p = 0; p < 4; ++p)
                pA[p] = *(const float4*)&A[(size_t)(ihalf * 64 + (t >> 4) + p * 16) * NC + kc + 64 + k4];
#pragma unroll
            for (int j = 0; j < 8; ++j)
                *(float4*)&pXe[j][0] = *(const float4*)&Xb[(size_t)(kc + 64 + kqx * 8 + j) * HW + pixbase + pix4];
        }
        // ---- compute phase ----
#pragma unroll
        for (int s = 0; s < 2; ++s) {
            bf16x8 ah[2], al[2], bh[4], bl[4];
#pragma unroll
            for (int mf = 0; mf < 2; ++mf) {
                const int r = wm * 32 + mf * 16 + (lane & 15);
                const int idx = r * 64 + swz(r, s * 4 + lq) * 8;
                ah[mf] = *(const bf16x8*)&Ah[idx];
                al[mf] = *(const bf16x8*)&Al[idx];
            }
#pragma unroll
            for (int nf = 0; nf < 4; ++nf) {
                const int pix = wn * 64 + nf * 16 + (lane & 15);
                const int idx = pix * 64 + swz(pix, s * 4 + lq) * 8;
                bh[nf] = *(const bf16x8*)&Xh[idx];
                bl[nf] = *(const bf16x8*)&Xl[idx];
            }
#pragma unroll
            for (int mf = 0; mf < 2; ++mf)
#pragma unroll
                for (int nf = 0; nf < 4; ++nf) {
                    acc[mf][nf] = MFMA16(ah[mf], bh[nf], acc[mf][nf]);
                    acc[mf][nf] = MFMA16(ah[mf], bl[nf], acc[mf][nf]);
                    acc[mf][nf] = MFMA16(al[mf], bh[nf], acc[mf][nf]);
                }
        }
        __syncthreads();
    }
    // epilogue: +bias, split to bf16 planes [b][ihalf][pix][64]
#pragma unroll
    for (int mf = 0; mf < 2; ++mf) {
        const int il0 = wm * 32 + mf * 16 + lq * 4;           // 0..63
        const int gi0 = ihalf * 64 + il0;
        const float b0 = abias[gi0], b1 = abias[gi0 + 1], b2 = abias[gi0 + 2], b3 = abias[gi0 + 3];
#pragma unroll
        for (int nf = 0; nf < 4; ++nf) {
            const int pix = pixbase + wn * 64 + nf * 16 + (lane & 15);
            const float v0 = acc[mf][nf][0] + b0;
            const float v1 = acc[mf][nf][1] + b1;
            const float v2 = acc[mf][nf][2] + b2;
            const float v3 = acc[mf][nf][3] + b3;
            unsigned hp0, lp0, hp1, lp1;
            split2pack(v0, v1, hp0, lp0);
            split2pack(v2, v3, hp1, lp1);
            const size_t o = ((size_t)(b * 2 + ihalf) * HW + pix) * 64 + il0;
            *(uint2*)&outH[o] = make_uint2(hp0, hp1);
            *(uint2*)&outL[o] = make_uint2(lp0, lp1);
        }
    }
}

// ---------------------------------------------------------------------------
// fused g+phi GEMM + 2x2 maxpool, reg-prefetch pipeline.
// ---------------------------------------------------------------------------
__global__ __launch_bounds__(256, 2)
void k_gphi(const float* __restrict__ Ag, const float* __restrict__ gbias,
            const float* __restrict__ Ap, const float* __restrict__ pbias,
            const float* __restrict__ X,
            float* __restrict__ gpout, float* __restrict__ ppout)
{
    __shared__ unsigned short Agh[64 * 64], Agl[64 * 64], Aph[64 * 64], Apl[64 * 64];
    __shared__ unsigned short Xh[128 * 64], Xl[128 * 64];
    const int t = threadIdx.x;
    const int lane = t & 63;
    const int lq = lane >> 4;
    const int b = blockIdx.z;
    const int ihalf = blockIdx.y;
    const int pr = blockIdx.x;
    const int pixbase = pr * 128;
    const int wm = (t >> 7) & 1;
    const int wn = (t >> 6) & 1;
    const float* Xb = X + (size_t)b * NC * HW;

    const int k4 = (t & 15) * 4;
    const int kqa = k4 >> 3, ina = k4 & 7;
    const int kqx = t >> 5;
    const int pix4 = (t & 31) * 4;

    f32x4 accg[2][4], accp[2][4];
#pragma unroll
    for (int i = 0; i < 2; ++i)
#pragma unroll
        for (int j = 0; j < 4; ++j) { accg[i][j] = (f32x4)(0.f); accp[i][j] = (f32x4)(0.f); }

    const int nbase[4] = {wn * 32, wn * 32 + 16, 64 + wn * 32, 64 + wn * 32 + 16};

    float4 pAg[4], pAp[4];
    float pXe[8][4];
#pragma unroll
    for (int p = 0; p < 4; ++p) {
        const size_t ro = (size_t)(ihalf * 64 + (t >> 4) + p * 16) * NC + k4;
        pAg[p] = *(const float4*)&Ag[ro];
        pAp[p] = *(const float4*)&Ap[ro];
    }
#pragma unroll
    for (int j = 0; j < 8; ++j)
        *(float4*)&pXe[j][0] = *(const float4*)&Xb[(size_t)(kqx * 8 + j) * HW + pixbase + pix4];

#pragma unroll 1
    for (int kc = 0; kc < NC; kc += 64) {
#pragma unroll
        for (int p = 0; p < 4; ++p) {
            const int r = (t >> 4) + p * 16;
            const int idx = r * 64 + swz(r, kqa) * 8 + ina;
            unsigned hp0, lp0, hp1, lp1;
            split2pack(pAg[p].x, pAg[p].y, hp0, lp0);
            split2pack(pAg[p].z, pAg[p].w, hp1, lp1);
            *(uint2*)&Agh[idx] = make_uint2(hp0, hp1);
            *(uint2*)&Agl[idx] = make_uint2(lp0, lp1);
            split2pack(pAp[p].x, pAp[p].y, hp0, lp0);
            split2pack(pAp[p].z, pAp[p].w, hp1, lp1);
            *(uint2*)&Aph[idx] = make_uint2(hp0, hp1);
            *(uint2*)&Apl[idx] = make_uint2(lp0, lp1);
        }
#pragma unroll
        for (int p = 0; p < 4; ++p) {
            unsigned hp[4], lp[4];
#pragma unroll
            for (int j2 = 0; j2 < 4; ++j2)
                split2pack(pXe[2 * j2][p], pXe[2 * j2 + 1][p], hp[j2], lp[j2]);
            const int pix = pix4 + p;
            const int idx = pix * 64 + swz(pix, kqx) * 8;
            *(uint4*)&Xh[idx] = make_uint4(hp[0], hp[1], hp[2], hp[3]);
            *(uint4*)&Xl[idx] = make_uint4(lp[0], lp[1], lp[2], lp[3]);
        }
        __syncthreads();
        if (kc + 64 < NC) {
#pragma unroll
            for (int p = 0; p < 4; ++p) {
                const size_t ro = (size_t)(ihalf * 64 + (t >> 4) + p * 16) * NC + kc + 64 + k4;
                pAg[p] = *(const float4*)&Ag[ro];
                pAp[p] = *(const float4*)&Ap[ro];
            }
#pragma unroll
            for (int j = 0; j < 8; ++j)
                *(float4*)&pXe[j][0] = *(const float4*)&Xb[(size_t)(kc + 64 + kqx * 8 + j) * HW + pixbase + pix4];
        }
#pragma unroll
        for (int s = 0; s < 2; ++s) {
            bf16x8 agh[2], agl[2], aph[2], apl[2], bh[4], bl[4];
#pragma unroll
            for (int mf = 0; mf < 2; ++mf) {
                const int r = wm * 32 + mf * 16 + (lane & 15);
                const int idx = r * 64 + swz(r, s * 4 + lq) * 8;
                agh[mf] = *(const bf16x8*)&Agh[idx];
                agl[mf] = *(const bf16x8*)&Agl[idx];
                aph[mf] = *(const bf16x8*)&Aph[idx];
                apl[mf] = *(const bf16x8*)&Apl[idx];
            }
#pragma unroll
            for (int nf = 0; nf < 4; ++nf) {
                const int pix = nbase[nf] + (lane & 15);
                const int idx = pix * 64 + swz(pix, s * 4 + lq) * 8;
                bh[nf] = *(const bf16x8*)&Xh[idx];
                bl[nf] = *(const bf16x8*)&Xl[idx];
            }
#pragma unroll
            for (int mf = 0; mf < 2; ++mf)
#pragma unroll
                for (int nf = 0; nf < 4; ++nf) {
                    accg[mf][nf] = MFMA16(agh[mf], bh[nf], accg[mf][nf]);
                    accg[mf][nf] = MFMA16(agh[mf], bl[nf], accg[mf][nf]);
                    accg[mf][nf] = MFMA16(agl[mf], bh[nf], accg[mf][nf]);
                    accp[mf][nf] = MFMA16(aph[mf], bh[nf], accp[mf][nf]);
                    accp[mf][nf] = MFMA16(aph[mf], bl[nf], accp[mf][nf]);
                    accp[mf][nf] = MFMA16(apl[mf], bh[nf], accp[mf][nf]);
                }
        }
        __syncthreads();
    }
#pragma unroll
    for (int which = 0; which < 2; ++which) {
        const float* bias = which ? pbias : gbias;
        float* dst = which ? ppout : gpout;
#pragma unroll
        for (int mf = 0; mf < 2; ++mf) {
            const int i0 = ihalf * 64 + wm * 32 + mf * 16 + lq * 4;
#pragma unroll
            for (int nfc = 0; nfc < 2; ++nfc) {
                f32x4 v;
                if (which == 0) {
#pragma unroll
                    for (int r = 0; r < 4; ++r)
                        v[r] = fmaxf(accg[mf][nfc][r], accg[mf][nfc + 2][r]);
                } else {
#pragma unroll
                    for (int r = 0; r < 4; ++r)
                        v[r] = fmaxf(accp[mf][nfc][r], accp[mf][nfc + 2][r]);
                }
                float h[4];
#pragma unroll
                for (int r = 0; r < 4; ++r)
                    h[r] = fmaxf(v[r], __shfl_xor(v[r], 1));
                if ((lane & 1) == 0) {
                    const int pcol = wn * 16 + nfc * 8 + ((lane & 15) >> 1);
#pragma unroll
                    for (int r = 0; r < 4; ++r)
                        dst[((size_t)b * NI + i0 + r) * NP + pr * 32 + pcol] = h[r] + bias[i0 + r];
                }
            }
        }
    }
}

// ---------------------------------------------------------------------------
// M-partials fp32: mp[ck][b][j][i] = sum_{n in 32-chunk} gp[j,n]*pp[i,n]
// grid (32, 8) = 256 blocks.
// ---------------------------------------------------------------------------
__global__ __launch_bounds__(256)
void k_mpart(const float* __restrict__ G, const float* __restrict__ Ph,
             float* __restrict__ Mpart)
{
    __shared__ float Gs[32][132];
    __shared__ float Ps[32][132];
    const int t = threadIdx.x;
    const int ck = blockIdx.x;
    const int b = blockIdx.y;
    const int nbase = ck * 32;
    const float* Gb = G + (size_t)b * NI * NP;
    const float* Pb = Ph + (size_t)b * NI * NP;

    float acc[8][8];
#pragma unroll
    for (int i = 0; i < 8; ++i)
#pragma unroll
        for (int j = 0; j < 8; ++j) acc[i][j] = 0.f;

    const int j0 = (t >> 4) << 3;
    const int c0 = (t & 15) << 2;

    {
#pragma unroll
        for (int p = 0; p < 4; ++p) {
            const int r = p * 32 + (t >> 3);
            const int n4 = (t & 7) << 2;
            const float4 g = *(const float4*)&Gb[(size_t)r * NP + nbase + n4];
            Gs[n4 + 0][r] = g.x; Gs[n4 + 1][r] = g.y;
            Gs[n4 + 2][r] = g.z; Gs[n4 + 3][r] = g.w;
            const float4 f = *(const float4*)&Pb[(size_t)r * NP + nbase + n4];
            Ps[n4 + 0][r] = f.x; Ps[n4 + 1][r] = f.y;
            Ps[n4 + 2][r] = f.z; Ps[n4 + 3][r] = f.w;
        }
        __syncthreads();
#pragma unroll
        for (int nn = 0; nn < 32; ++nn) {
            const float4 a0 = *(const float4*)&Gs[nn][j0];
            const float4 a1 = *(const float4*)&Gs[nn][j0 + 4];
            const float4 b0 = *(const float4*)&Ps[nn][c0];
            const float4 b1 = *(const float4*)&Ps[nn][c0 + 64];
            const float av[8] = {a0.x, a0.y, a0.z, a0.w, a1.x, a1.y, a1.z, a1.w};
            const float bv[8] = {b0.x, b0.y, b0.z, b0.w, b1.x, b1.y, b1.z, b1.w};
#pragma unroll
            for (int i = 0; i < 8; ++i)
#pragma unroll
                for (int j = 0; j < 8; ++j)
                    acc[i][j] = fmaf(av[i], bv[j], acc[i][j]);
        }
    }

    float* Mb = Mpart + (size_t)(ck * NB + b) * (NI * NI);
#pragma unroll
    for (int jj = 0; jj < 8; ++jj) {
        float4 o0, o1;
        o0.x = acc[jj][0]; o0.y = acc[jj][1]; o0.z = acc[jj][2]; o0.w = acc[jj][3];
        o1.x = acc[jj][4]; o1.y = acc[jj][5]; o1.z = acc[jj][6]; o1.w = acc[jj][7];
        *(float4*)&Mb[(size_t)(j0 + jj) * NI + c0]      = o0;
        *(float4*)&Mb[(size_t)(j0 + jj) * NI + c0 + 64] = o1;
    }
}

// ---------------------------------------------------------------------------
// Reduce 32 partials -> M. grid 128 blocks x 256 thr, one float4 each.
// ---------------------------------------------------------------------------
__global__ __launch_bounds__(256)
void k_msum(const float* __restrict__ Mpart, float* __restrict__ M)
{
    const size_t idx4 = ((size_t)blockIdx.x * 256 + threadIdx.x) * 4;
    f32x4 s = (f32x4)(0.f);
#pragma unroll
    for (int ck = 0; ck < NCK; ++ck) {
        const float4 v = *(const float4*)&Mpart[(size_t)ck * NB * NI * NI + idx4];
        s[0] += v.x; s[1] += v.y; s[2] += v.z; s[3] += v.w;
    }
    float4 o; o.x = s[0]; o.y = s[1]; o.z = s[2]; o.w = s[3];
    *(float4*)&M[idx4] = o;
}

// ---------------------------------------------------------------------------
// P[c,i] = s_c/Np * sum_j W_w[c,j]*M[b][j][i].  grid (4, 8).
// ---------------------------------------------------------------------------
__global__ __launch_bounds__(256)
void k_pgemm(const float* __restrict__ M, const float* __restrict__ Wm,
             const float* __restrict__ bng, float* __restrict__ P)
{
    __shared__ float Ms[128][128];
    const int t = threadIdx.x;
    const int cbase = blockIdx.x * 64;
    const int b = blockIdx.y;
    const float* Mb = M + (size_t)b * NI * NI;

#pragma unroll
    for (int rep = 0; rep < 16; ++rep) {
        const int flat = rep * 256 + t;
        const int j = flat >> 5;
        const int i4 = (flat & 31) << 2;
        *(float4*)&Ms[j][i4] = *(const float4*)&Mb[(size_t)j * NI + i4];
    }
    __syncthreads();

    const float inv = 1.f / (float)NP;
    const int i0 = (t & 7) << 4;
#pragma unroll
    for (int pp = 0; pp < 2; ++pp) {
        const int c = cbase + pp * 32 + (t >> 3);
        const float* wrow = Wm + (size_t)c * NI;
        float a[16];
#pragma unroll
        for (int q = 0; q < 16; ++q) a[q] = 0.f;
#pragma unroll 4
        for (int j = 0; j < 128; ++j) {
            const float w = wrow[j];
            const float4 m0v = *(const float4*)&Ms[j][i0];
            const float4 m1v = *(const float4*)&Ms[j][i0 + 4];
            const float4 m2v = *(const float4*)&Ms[j][i0 + 8];
            const float4 m3v = *(const float4*)&Ms[j][i0 + 12];
            a[0]  = fmaf(w, m0v.x, a[0]);  a[1]  = fmaf(w, m0v.y, a[1]);
            a[2]  = fmaf(w, m0v.z, a[2]);  a[3]  = fmaf(w, m0v.w, a[3]);
            a[4]  = fmaf(w, m1v.x, a[4]);  a[5]  = fmaf(w, m1v.y, a[5]);
            a[6]  = fmaf(w, m1v.z, a[6]);  a[7]  = fmaf(w, m1v.w, a[7]);
            a[8]  = fmaf(w, m2v.x, a[8]);  a[9]  = fmaf(w, m2v.y, a[9]);
            a[10] = fmaf(w, m2v.z, a[10]); a[11] = fmaf(w, m2v.w, a[11]);
            a[12] = fmaf(w, m3v.x, a[12]); a[13] = fmaf(w, m3v.y, a[13]);
            a[14] = fmaf(w, m3v.z, a[14]); a[15] = fmaf(w, m3v.w, a[15]);
        }
        const float sc = bng[c] / sqrtf(1.f + BNEPS) * inv;
        float* Pp = P + ((size_t)b * NC + c) * NI + i0;
#pragma unroll
        for (int q = 0; q < 4; ++q) {
            float4 o;
            o.x = a[4 * q] * sc;     o.y = a[4 * q + 1] * sc;
            o.z = a[4 * q + 2] * sc; o.w = a[4 * q + 3] * sc;
            *(float4*)&Pp[4 * q] = o;
        }
    }
}

// ---------------------------------------------------------------------------
// final GEMM: out = P @ theta + beta_c + x.  theta from pre-split bf16 planes.
// tile 64c x 128pix, BK=64, reg-prefetch pipeline.
// ---------------------------------------------------------------------------
__global__ __launch_bounds__(256, 3)
void k_final(const float* __restrict__ P,
             const unsigned short* __restrict__ TTh, const unsigned short* __restrict__ TTl,
             const float* __restrict__ Wb, const float* __restrict__ bng,
             const float* __restrict__ bnb, const float* __restrict__ xres,
             float* __restrict__ out)
{
    __shared__ unsigned short Ph_[64 * 64], Pl_[64 * 64], Th[128 * 64], Tl[128 * 64];
    const int t = threadIdx.x;
    const int lane = t & 63;
    const int lq = lane >> 4;
    const int b = blockIdx.z;
    const int cbase = blockIdx.y * 64;
    const int pixbase = blockIdx.x * 128;
    const int wm = (t >> 7) & 1;
    const int wn = (t >> 6) & 1;
    const float* Pb = P + (size_t)b * NC * NI;

    const int k4 = (t & 15) * 4;          // P staging col
    const int kqa = k4 >> 3, ina = k4 & 7;
    const int kqt = t & 7;                // T staging: 16B unit in i
    const int pixt = t >> 3;              // 0..31, +pass*32

    f32x4 acc[2][4];
#pragma unroll
    for (int i = 0; i < 2; ++i)
#pragma unroll
        for (int j = 0; j < 4; ++j) acc[i][j] = (f32x4)(0.f);

    float4 pP[4];
    uint4 pTh[4], pTl[4];
#pragma unroll
    for (int p = 0; p < 4; ++p)
        pP[p] = *(const float4*)&Pb[(size_t)(cbase + (t >> 4) + p * 16) * NI + k4];
#pragma unroll
    for (int p = 0; p < 4; ++p) {
        const size_t o = ((size_t)(b * 2 + 0) * HW + pixbase + pixt + p * 32) * 64 + kqt * 8;
        pTh[p] = *(const uint4*)&TTh[o];
        pTl[p] = *(const uint4*)&TTl[o];
    }

#pragma unroll 1
    for (int ic = 0; ic < NI; ic += 64) {
#pragma unroll
        for (int p = 0; p < 4; ++p) {
            const int r = (t >> 4) + p * 16;
            unsigned hp0, lp0, hp1, lp1;
            split2pack(pP[p].x, pP[p].y, hp0, lp0);
            split2pack(pP[p].z, pP[p].w, hp1, lp1);
            const int idx = r * 64 + swz(r, kqa) * 8 + ina;
            *(uint2*)&Ph_[idx] = make_uint2(hp0, hp1);
            *(uint2*)&Pl_[idx] = make_uint2(lp0, lp1);
        }
#pragma unroll
        for (int p = 0; p < 4; ++p) {
            const int pix = pixt + p * 32;
            const int idx = pix * 64 + swz(pix, kqt) * 8;
            *(uint4*)&Th[idx] = pTh[p];
            *(uint4*)&Tl[idx] = pTl[p];
        }
        __syncthreads();
        if (ic + 64 < NI) {
#pragma unroll
            for (int p = 0; p < 4; ++p)
                pP[p] = *(const float4*)&Pb[(size_t)(cbase + (t >> 4) + p * 16) * NI + ic + 64 + k4];
#pragma unroll
            for (int p = 0; p < 4; ++p) {
                const size_t o = ((size_t)(b * 2 + 1) * HW + pixbase + pixt + p * 32) * 64 + kqt * 8;
                pTh[p] = *(const uint4*)&TTh[o];
                pTl[p] = *(const uint4*)&TTl[o];
            }
        }
#pragma unroll
        for (int s = 0; s < 2; ++s) {
            bf16x8 ah[2], al[2], bh[4], bl[4];
#pragma unroll
            for (int mf = 0; mf < 2; ++mf) {
                const int r = wm * 32 + mf * 16 + (lane & 15);
                const int idx = r * 64 + swz(r, s * 4 + lq) * 8;
                ah[mf] = *(const bf16x8*)&Ph_[idx];
                al[mf] = *(const bf16x8*)&Pl_[idx];
            }
#pragma unroll
            for (int nf = 0; nf < 4; ++nf) {
                const int pix = wn * 64 + nf * 16 + (lane & 15);
                const int idx = pix * 64 + swz(pix, s * 4 + lq) * 8;
                bh[nf] = *(const bf16x8*)&Th[idx];
                bl[nf] = *(const bf16x8*)&Tl[idx];
            }
#pragma unroll
            for (int mf = 0; mf < 2; ++mf)
#pragma unroll
                for (int nf = 0; nf < 4; ++nf) {
                    acc[mf][nf] = MFMA16(ah[mf], bh[nf], acc[mf][nf]);
                    acc[mf][nf] = MFMA16(ah[mf], bl[nf], acc[mf][nf]);
                    acc[mf][nf] = MFMA16(al[mf], bh[nf], acc[mf][nf]);
                }
        }
        __syncthreads();
    }
    const float rs = rsqrtf(1.f + BNEPS);
#pragma unroll
    for (int mf = 0; mf < 2; ++mf) {
        const int c0 = cbase + wm * 32 + mf * 16 + lq * 4;
        float beta[4];
#pragma unroll
        for (int r = 0; r < 4; ++r) {
            const float scv = bng[c0 + r] * rs;
            beta[r] = scv * Wb[c0 + r] + bnb[c0 + r];
        }
#pragma unroll
        for (int nf = 0; nf < 4; ++nf) {
            const int pix = pixbase + wn * 64 + nf * 16 + (lane & 15);
#pragma unroll
            for (int r = 0; r < 4; ++r) {
                const size_t o = ((size_t)b * NC + c0 + r) * HW + pix;
                out[o] = acc[mf][nf][r] + beta[r] + xres[o];
            }
        }
    }
}

extern "C" void kernel_launch(void* const* d_in, const int* in_sizes, int n_in,
                              void* d_out, int out_size, void* d_ws, size_t ws_size,
                              hipStream_t stream)
{
    const float* x    = (const float*)d_in[0];
    const float* y    = (const float*)d_in[1];
    const float* g_w  = (const float*)d_in[2];
    const float* g_b  = (const float*)d_in[3];
    const float* th_w = (const float*)d_in[4];
    const float* th_b = (const float*)d_in[5];
    const float* ph_w = (const float*)d_in[6];
    const float* ph_b = (const float*)d_in[7];
    const float* Wm   = (const float*)d_in[8];
    const float* Wb   = (const float*)d_in[9];
    const float* bng  = (const float*)d_in[10];
    const float* bnb  = (const float*)d_in[11];
    float* out = (float*)d_out;
    char* ws = (char*)d_ws;

    unsigned short* TTh = (unsigned short*)ws;                       // 8*2*4096*64 sh
    unsigned short* TTl = TTh + (size_t)NB * 2 * HW * 64;            // 8.4 MB each
    float* gp = (float*)(TTl + (size_t)NB * 2 * HW * 64);            // 8*128*1024 f32
    float* pp = gp + (size_t)NB * NI * NP;
    float* mp = pp + (size_t)NB * NI * NP;                           // 32*8*128*128 f32
    float* M  = mp + (size_t)NCK * NB * NI * NI;                     // 8*128*128 f32
    float* P  = M  + (size_t)NB * NI * NI;                           // 8*256*128 f32

    const dim3 blk(256);
    k_theta<<<dim3(32, 2, NB), blk, 0, stream>>>(th_w, th_b, x, TTh, TTl);
    k_gphi<<<dim3(32, 2, NB), blk, 0, stream>>>(g_w, g_b, ph_w, ph_b, y, gp, pp);
    k_mpart<<<dim3(NCK, NB), blk, 0, stream>>>(gp, pp, mp);
    k_msum<<<dim3(NB * NI * NI / 1024), blk, 0, stream>>>(mp, M);
    k_pgemm<<<dim3(4, NB), blk, 0, stream>>>(M, Wm, bng, P);
    k_final<<<dim3(32, 4, NB), blk, 0, stream>>>(P, TTh, TTl, Wb, bng, bnb, x, out);
}

// Round 6
// 182.689 us; speedup vs baseline: 1.5516x; 1.1776x over previous
//
#include <hip/hip_runtime.h>
#include <math.h>

// NonLocalBlock2D, reassociated, plain-bf16 MFMA (fp32 accum):
//   TT  = bf16 pre-swizzled tiles of (theta_w @ x + theta_b)^T  [B,64tiles,64pix,128i]
//   gp  = maxpool2(g_w   @ y + g_b)    [B,128,1024] f32
//   pp  = maxpool2(phi_w @ y + phi_b)  [B,128,1024] f32
//   mp[ck] = partial  sum_{n in ck} gp[j,n]*pp[i,n]  (32 chunks of 32)
//   M = sum_ck mp[ck]                  [B,128,128] f32
//   Pp = bf16 pre-swizzled tiles of  s_c/Np * W_w @ M   [B,4tiles,64c,128i]
//   out = Pp @ TT + (s_c*W_b+bn_beta) + x   [B,256,4096] f32
// R5 bug: k_final staged only half of each 8192-entry tile (p<2); fixed to p<4.

namespace {
constexpr int NB = 8;
constexpr int NC = 256;
constexpr int NI = 128;
constexpr int HW = 4096;
constexpr int NP = 1024;
constexpr int NCK = 32;
constexpr float BNEPS = 1e-5f;
}

typedef __bf16 bf16x8 __attribute__((ext_vector_type(8)));
typedef float f32x4 __attribute__((ext_vector_type(4)));
typedef unsigned short us;

#define MFMA16(a, b, c) __builtin_amdgcn_mfma_f32_16x16x32_bf16((a), (b), (c), 0, 0, 0)

__device__ __forceinline__ unsigned rne_hi_bits(float f) {
    unsigned b = __float_as_uint(f);
    return (b + 0x7fffu + ((b >> 16) & 1u)) & 0xffff0000u;
}
__device__ __forceinline__ unsigned pack2bf(float e0, float e1) {
    return (rne_hi_bits(e0) >> 16) | (rne_hi_bits(e1) & 0xffff0000u);
}
// staging swizzle: rows of 64 bf16 (128B) = 8 slots of 16B
__device__ __forceinline__ int swz(int row, int kq) {
    return kq ^ ((row ^ (row >> 2)) & 7);
}
// tile-image swizzle: rows of 128 bf16 (256B) = 16 slots of 16B; XOR low 3
// bits only (keeps 128B halves intact -> full-line global writes)
__device__ __forceinline__ int swz16(int row, int q) {
    return q ^ (row & 7);
}

// ---------------------------------------------------------------------------
// theta: TT tile (b, pixtile) = bf16[(pix 64)][(i 128) swizzled]
// block: 128i x 64pix, BK=64 over NC, 4 waves (2i x 2pix), reg-prefetch.
// ---------------------------------------------------------------------------
__global__ __launch_bounds__(256)
void k_theta(const float* __restrict__ A, const float* __restrict__ abias,
             const float* __restrict__ X, us* __restrict__ TT)
{
    __shared__ char smem[24576];
    us* As = (us*)smem;            // 128 x 64 bf16 (16 KB)
    us* Xs = (us*)(smem + 16384);  // 64 x 64 bf16 (8 KB)
    const int t = threadIdx.x, lane = t & 63, l15 = lane & 15, lq = lane >> 4;
    const int w = t >> 6, wi = w & 1, wp = w >> 1;
    const int b = blockIdx.z, pixbase = blockIdx.x * 64;
    const float* Xb = X + (size_t)b * NC * HW;

    const int k4 = (t & 15) * 4, kqa = k4 >> 3, ina = k4 & 7;
    const int arow = t >> 4;
    const int ks = t >> 4, pix4 = (t & 15) * 4;
    const int kqx = ks >> 1, inx = (ks & 1) * 4;

    f32x4 acc[4][2];
#pragma unroll
    for (int i = 0; i < 4; ++i)
#pragma unroll
        for (int j = 0; j < 2; ++j) acc[i][j] = (f32x4)(0.f);

    float4 pA[8];
    float pXe[4][4];
#pragma unroll
    for (int p = 0; p < 8; ++p)
        pA[p] = *(const float4*)&A[(size_t)(arow + p * 16) * NC + k4];
#pragma unroll
    for (int j = 0; j < 4; ++j) {
        const float4 tv = *(const float4*)&Xb[(size_t)(ks * 4 + j) * HW + pixbase + pix4];
        pXe[j][0] = tv.x; pXe[j][1] = tv.y; pXe[j][2] = tv.z; pXe[j][3] = tv.w;
    }

#pragma unroll 1
    for (int kc = 0; kc < NC; kc += 64) {
#pragma unroll
        for (int p = 0; p < 8; ++p) {
            const int r = arow + p * 16;
            *(uint2*)&As[r * 64 + swz(r, kqa) * 8 + ina] =
                make_uint2(pack2bf(pA[p].x, pA[p].y), pack2bf(pA[p].z, pA[p].w));
        }
#pragma unroll
        for (int p = 0; p < 4; ++p) {
            const int pix = pix4 + p;
            *(uint2*)&Xs[pix * 64 + swz(pix, kqx) * 8 + inx] =
                make_uint2(pack2bf(pXe[0][p], pXe[1][p]), pack2bf(pXe[2][p], pXe[3][p]));
        }
        __syncthreads();
        if (kc + 64 < NC) {
#pragma unroll
            for (int p = 0; p < 8; ++p)
                pA[p] = *(const float4*)&A[(size_t)(arow + p * 16) * NC + kc + 64 + k4];
#pragma unroll
            for (int j = 0; j < 4; ++j) {
                const float4 tv = *(const float4*)&Xb[(size_t)(kc + 64 + ks * 4 + j) * HW + pixbase + pix4];
                pXe[j][0] = tv.x; pXe[j][1] = tv.y; pXe[j][2] = tv.z; pXe[j][3] = tv.w;
            }
        }
#pragma unroll
        for (int s = 0; s < 2; ++s) {
            bf16x8 a[4], bb[2];
#pragma unroll
            for (int mf = 0; mf < 4; ++mf) {
                const int r = wi * 64 + mf * 16 + l15;
                a[mf] = *(const bf16x8*)&As[r * 64 + swz(r, s * 4 + lq) * 8];
            }
#pragma unroll
            for (int nf = 0; nf < 2; ++nf) {
                const int pr = wp * 32 + nf * 16 + l15;
                bb[nf] = *(const bf16x8*)&Xs[pr * 64 + swz(pr, s * 4 + lq) * 8];
            }
#pragma unroll
            for (int mf = 0; mf < 4; ++mf)
#pragma unroll
                for (int nf = 0; nf < 2; ++nf)
                    acc[mf][nf] = MFMA16(a[mf], bb[nf], acc[mf][nf]);
        }
        __syncthreads();
    }
    // epilogue: +bias, cvt bf16, scatter into swizzled tile image, copy out
    us* Ts = (us*)smem;   // 64pix x 128i (16 KB), aliases As/Xs
#pragma unroll
    for (int mf = 0; mf < 4; ++mf) {
        const int i0 = wi * 64 + mf * 16 + lq * 4;
        const float b0 = abias[i0], b1 = abias[i0 + 1], b2 = abias[i0 + 2], b3 = abias[i0 + 3];
        const int q = i0 >> 3, inn = i0 & 7;
#pragma unroll
        for (int nf = 0; nf < 2; ++nf) {
            const int pix = wp * 32 + nf * 16 + l15;
            *(uint2*)&Ts[pix * 128 + swz16(pix, q) * 8 + inn] =
                make_uint2(pack2bf(acc[mf][nf][0] + b0, acc[mf][nf][1] + b1),
                           pack2bf(acc[mf][nf][2] + b2, acc[mf][nf][3] + b3));
        }
    }
    __syncthreads();
    us* dst = TT + ((size_t)b * 64 + blockIdx.x) * 8192;
#pragma unroll
    for (int p = 0; p < 4; ++p) {
        const int flat = p * 256 + t;
        *(uint4*)&dst[flat * 8] = *(const uint4*)&Ts[flat * 8];
    }
}

// ---------------------------------------------------------------------------
// fused g+phi GEMM + 2x2 maxpool (proven structure, single bf16 plane).
// ---------------------------------------------------------------------------
__global__ __launch_bounds__(256)
void k_gphi(const float* __restrict__ Ag, const float* __restrict__ gbias,
            const float* __restrict__ Ap, const float* __restrict__ pbias,
            const float* __restrict__ X,
            float* __restrict__ gpout, float* __restrict__ ppout)
{
    __shared__ us Ags[64 * 64], Aps[64 * 64], Xs[128 * 64];
    const int t = threadIdx.x, lane = t & 63, l15 = lane & 15, lq = lane >> 4;
    const int b = blockIdx.z, ihalf = blockIdx.y, pr = blockIdx.x;
    const int pixbase = pr * 128;
    const int wm = (t >> 7) & 1, wn = (t >> 6) & 1;
    const float* Xb = X + (size_t)b * NC * HW;

    const int k4 = (t & 15) * 4, kqa = k4 >> 3, ina = k4 & 7;
    const int kqx = t >> 5, pix4 = (t & 31) * 4;

    f32x4 accg[2][4], accp[2][4];
#pragma unroll
    for (int i = 0; i < 2; ++i)
#pragma unroll
        for (int j = 0; j < 4; ++j) { accg[i][j] = (f32x4)(0.f); accp[i][j] = (f32x4)(0.f); }

    const int nbase[4] = {wn * 32, wn * 32 + 16, 64 + wn * 32, 64 + wn * 32 + 16};

    float4 pAg[4], pAp[4];
    float pXe[8][4];
#pragma unroll
    for (int p = 0; p < 4; ++p) {
        const size_t ro = (size_t)(ihalf * 64 + (t >> 4) + p * 16) * NC + k4;
        pAg[p] = *(const float4*)&Ag[ro];
        pAp[p] = *(const float4*)&Ap[ro];
    }
#pragma unroll
    for (int j = 0; j < 8; ++j) {
        const float4 tv = *(const float4*)&Xb[(size_t)(kqx * 8 + j) * HW + pixbase + pix4];
        pXe[j][0] = tv.x; pXe[j][1] = tv.y; pXe[j][2] = tv.z; pXe[j][3] = tv.w;
    }

#pragma unroll 1
    for (int kc = 0; kc < NC; kc += 64) {
#pragma unroll
        for (int p = 0; p < 4; ++p) {
            const int r = (t >> 4) + p * 16;
            const int idx = r * 64 + swz(r, kqa) * 8 + ina;
            *(uint2*)&Ags[idx] = make_uint2(pack2bf(pAg[p].x, pAg[p].y), pack2bf(pAg[p].z, pAg[p].w));
            *(uint2*)&Aps[idx] = make_uint2(pack2bf(pAp[p].x, pAp[p].y), pack2bf(pAp[p].z, pAp[p].w));
        }
#pragma unroll
        for (int p = 0; p < 4; ++p) {
            const int pix = pix4 + p;
            *(uint4*)&Xs[pix * 64 + swz(pix, kqx) * 8] =
                make_uint4(pack2bf(pXe[0][p], pXe[1][p]), pack2bf(pXe[2][p], pXe[3][p]),
                           pack2bf(pXe[4][p], pXe[5][p]), pack2bf(pXe[6][p], pXe[7][p]));
        }
        __syncthreads();
        if (kc + 64 < NC) {
#pragma unroll
            for (int p = 0; p < 4; ++p) {
                const size_t ro = (size_t)(ihalf * 64 + (t >> 4) + p * 16) * NC + kc + 64 + k4;
                pAg[p] = *(const float4*)&Ag[ro];
                pAp[p] = *(const float4*)&Ap[ro];
            }
#pragma unroll
            for (int j = 0; j < 8; ++j) {
                const float4 tv = *(const float4*)&Xb[(size_t)(kc + 64 + kqx * 8 + j) * HW + pixbase + pix4];
                pXe[j][0] = tv.x; pXe[j][1] = tv.y; pXe[j][2] = tv.z; pXe[j][3] = tv.w;
            }
        }
#pragma unroll
        for (int s = 0; s < 2; ++s) {
            bf16x8 ag[2], ap[2], bb[4];
#pragma unroll
            for (int mf = 0; mf < 2; ++mf) {
                const int r = wm * 32 + mf * 16 + l15;
                const int idx = r * 64 + swz(r, s * 4 + lq) * 8;
                ag[mf] = *(const bf16x8*)&Ags[idx];
                ap[mf] = *(const bf16x8*)&Aps[idx];
            }
#pragma unroll
            for (int nf = 0; nf < 4; ++nf) {
                const int pix = nbase[nf] + l15;
                bb[nf] = *(const bf16x8*)&Xs[pix * 64 + swz(pix, s * 4 + lq) * 8];
            }
#pragma unroll
            for (int mf = 0; mf < 2; ++mf)
#pragma unroll
                for (int nf = 0; nf < 4; ++nf) {
                    accg[mf][nf] = MFMA16(ag[mf], bb[nf], accg[mf][nf]);
                    accp[mf][nf] = MFMA16(ap[mf], bb[nf], accp[mf][nf]);
                }
        }
        __syncthreads();
    }
#pragma unroll
    for (int which = 0; which < 2; ++which) {
        const float* bias = which ? pbias : gbias;
        float* dst = which ? ppout : gpout;
#pragma unroll
        for (int mf = 0; mf < 2; ++mf) {
            const int i0 = ihalf * 64 + wm * 32 + mf * 16 + lq * 4;
#pragma unroll
            for (int nfc = 0; nfc < 2; ++nfc) {
                f32x4 v;
                if (which == 0) {
#pragma unroll
                    for (int r = 0; r < 4; ++r)
                        v[r] = fmaxf(accg[mf][nfc][r], accg[mf][nfc + 2][r]);
                } else {
#pragma unroll
                    for (int r = 0; r < 4; ++r)
                        v[r] = fmaxf(accp[mf][nfc][r], accp[mf][nfc + 2][r]);
                }
                float h[4];
#pragma unroll
                for (int r = 0; r < 4; ++r)
                    h[r] = fmaxf(v[r], __shfl_xor(v[r], 1));
                if ((lane & 1) == 0) {
                    const int pcol = wn * 16 + nfc * 8 + (l15 >> 1);
#pragma unroll
                    for (int r = 0; r < 4; ++r)
                        dst[((size_t)b * NI + i0 + r) * NP + pr * 32 + pcol] = h[r] + bias[i0 + r];
                }
            }
        }
    }
}

// ---------------------------------------------------------------------------
// M-partials fp32 (unchanged).
// ---------------------------------------------------------------------------
__global__ __launch_bounds__(256)
void k_mpart(const float* __restrict__ G, const float* __restrict__ Ph,
             float* __restrict__ Mpart)
{
    __shared__ float Gs[32][132];
    __shared__ float Ps[32][132];
    const int t = threadIdx.x;
    const int ck = blockIdx.x;
    const int b = blockIdx.y;
    const int nbase = ck * 32;
    const float* Gb = G + (size_t)b * NI * NP;
    const float* Pb = Ph + (size_t)b * NI * NP;

    float acc[8][8];
#pragma unroll
    for (int i = 0; i < 8; ++i)
#pragma unroll
        for (int j = 0; j < 8; ++j) acc[i][j] = 0.f;

    const int j0 = (t >> 4) << 3;
    const int c0 = (t & 15) << 2;

#pragma unroll
    for (int p = 0; p < 4; ++p) {
        const int r = p * 32 + (t >> 3);
        const int n4 = (t & 7) << 2;
        const float4 g = *(const float4*)&Gb[(size_t)r * NP + nbase + n4];
        Gs[n4 + 0][r] = g.x; Gs[n4 + 1][r] = g.y;
        Gs[n4 + 2][r] = g.z; Gs[n4 + 3][r] = g.w;
        const float4 f = *(const float4*)&Pb[(size_t)r * NP + nbase + n4];
        Ps[n4 + 0][r] = f.x; Ps[n4 + 1][r] = f.y;
        Ps[n4 + 2][r] = f.z; Ps[n4 + 3][r] = f.w;
    }
    __syncthreads();
#pragma unroll
    for (int nn = 0; nn < 32; ++nn) {
        const float4 a0 = *(const float4*)&Gs[nn][j0];
        const float4 a1 = *(const float4*)&Gs[nn][j0 + 4];
        const float4 b0 = *(const float4*)&Ps[nn][c0];
        const float4 b1 = *(const float4*)&Ps[nn][c0 + 64];
        const float av[8] = {a0.x, a0.y, a0.z, a0.w, a1.x, a1.y, a1.z, a1.w};
        const float bv[8] = {b0.x, b0.y, b0.z, b0.w, b1.x, b1.y, b1.z, b1.w};
#pragma unroll
        for (int i = 0; i < 8; ++i)
#pragma unroll
            for (int j = 0; j < 8; ++j)
                acc[i][j] = fmaf(av[i], bv[j], acc[i][j]);
    }

    float* Mb = Mpart + (size_t)(ck * NB + b) * (NI * NI);
#pragma unroll
    for (int jj = 0; jj < 8; ++jj) {
        float4 o0, o1;
        o0.x = acc[jj][0]; o0.y = acc[jj][1]; o0.z = acc[jj][2]; o0.w = acc[jj][3];
        o1.x = acc[jj][4]; o1.y = acc[jj][5]; o1.z = acc[jj][6]; o1.w = acc[jj][7];
        *(float4*)&Mb[(size_t)(j0 + jj) * NI + c0]      = o0;
        *(float4*)&Mb[(size_t)(j0 + jj) * NI + c0 + 64] = o1;
    }
}

// ---------------------------------------------------------------------------
// Reduce 32 partials -> M (unchanged).
// ---------------------------------------------------------------------------
__global__ __launch_bounds__(256)
void k_msum(const float* __restrict__ Mpart, float* __restrict__ M)
{
    const size_t idx4 = ((size_t)blockIdx.x * 256 + threadIdx.x) * 4;
    f32x4 s = (f32x4)(0.f);
#pragma unroll
    for (int ck = 0; ck < NCK; ++ck) {
        const float4 v = *(const float4*)&Mpart[(size_t)ck * NB * NI * NI + idx4];
        s[0] += v.x; s[1] += v.y; s[2] += v.z; s[3] += v.w;
    }
    float4 o; o.x = s[0]; o.y = s[1]; o.z = s[2]; o.w = s[3];
    *(float4*)&M[idx4] = o;
}

// ---------------------------------------------------------------------------
// Pp tile (b, ctile) = bf16[(c 64)][(i 128) swizzled] of s_c/Np * W_w @ M
// ---------------------------------------------------------------------------
__global__ __launch_bounds__(256)
void k_pgemm(const float* __restrict__ M, const float* __restrict__ Wm,
             const float* __restrict__ bng, us* __restrict__ Pp)
{
    __shared__ float Ms[128][128];
    const int t = threadIdx.x;
    const int cbase = blockIdx.x * 64;
    const int b = blockIdx.y;
    const float* Mb = M + (size_t)b * NI * NI;

#pragma unroll
    for (int rep = 0; rep < 16; ++rep) {
        const int flat = rep * 256 + t;
        const int j = flat >> 5;
        const int i4 = (flat & 31) << 2;
        *(float4*)&Ms[j][i4] = *(const float4*)&Mb[(size_t)j * NI + i4];
    }
    __syncthreads();

    const float inv = 1.f / (float)NP;
    const int i0 = (t & 7) << 4;
#pragma unroll
    for (int pp = 0; pp < 2; ++pp) {
        const int c = cbase + pp * 32 + (t >> 3);
        const float* wrow = Wm + (size_t)c * NI;
        float a[16];
#pragma unroll
        for (int q = 0; q < 16; ++q) a[q] = 0.f;
#pragma unroll 4
        for (int j = 0; j < 128; ++j) {
            const float w = wrow[j];
            const float4 m0v = *(const float4*)&Ms[j][i0];
            const float4 m1v = *(const float4*)&Ms[j][i0 + 4];
            const float4 m2v = *(const float4*)&Ms[j][i0 + 8];
            const float4 m3v = *(const float4*)&Ms[j][i0 + 12];
            a[0]  = fmaf(w, m0v.x, a[0]);  a[1]  = fmaf(w, m0v.y, a[1]);
            a[2]  = fmaf(w, m0v.z, a[2]);  a[3]  = fmaf(w, m0v.w, a[3]);
            a[4]  = fmaf(w, m1v.x, a[4]);  a[5]  = fmaf(w, m1v.y, a[5]);
            a[6]  = fmaf(w, m1v.z, a[6]);  a[7]  = fmaf(w, m1v.w, a[7]);
            a[8]  = fmaf(w, m2v.x, a[8]);  a[9]  = fmaf(w, m2v.y, a[9]);
            a[10] = fmaf(w, m2v.z, a[10]); a[11] = fmaf(w, m2v.w, a[11]);
            a[12] = fmaf(w, m3v.x, a[12]); a[13] = fmaf(w, m3v.y, a[13]);
            a[14] = fmaf(w, m3v.z, a[14]); a[15] = fmaf(w, m3v.w, a[15]);
        }
        const float sc = bng[c] / sqrtf(1.f + BNEPS) * inv;
        const int r = pp * 32 + (t >> 3);
        const int q0 = (t & 7) * 2;
        us* dst = Pp + ((size_t)b * 4 + blockIdx.x) * 8192 + r * 128;
        *(uint4*)&dst[swz16(r, q0) * 8] =
            make_uint4(pack2bf(a[0] * sc, a[1] * sc), pack2bf(a[2] * sc, a[3] * sc),
                       pack2bf(a[4] * sc, a[5] * sc), pack2bf(a[6] * sc, a[7] * sc));
        *(uint4*)&dst[swz16(r, q0 + 1) * 8] =
            make_uint4(pack2bf(a[8] * sc, a[9] * sc), pack2bf(a[10] * sc, a[11] * sc),
                       pack2bf(a[12] * sc, a[13] * sc), pack2bf(a[14] * sc, a[15] * sc));
    }
}

// ---------------------------------------------------------------------------
// final: out[64c x 64pix tile] = Pp_tile @ TT_tile + beta_c + x
// staging = pure linear uint4 copy (tiles pre-swizzled); LDS-transpose
// epilogue -> float4 coalesced stores.
// ---------------------------------------------------------------------------
__global__ __launch_bounds__(256)
void k_final(const us* __restrict__ Pp, const us* __restrict__ TT,
             const float* __restrict__ Wb, const float* __restrict__ bng,
             const float* __restrict__ bnb, const float* __restrict__ xres,
             float* __restrict__ out)
{
    __shared__ char smem[32768];
    us* As = (us*)smem;             // 64c x 128i (16 KB)
    us* Bs = (us*)(smem + 16384);   // 64p x 128i (16 KB)
    const int t = threadIdx.x, lane = t & 63, l15 = lane & 15, lq = lane >> 4;
    const int w = t >> 6, wc = w & 1, wp = w >> 1;
    const int b = blockIdx.z, ct = blockIdx.y, pt = blockIdx.x;
    const us* Atile = Pp + ((size_t)b * 4 + ct) * 8192;
    const us* Btile = TT + ((size_t)b * 64 + pt) * 8192;

#pragma unroll
    for (int p = 0; p < 4; ++p) {   // R5 FIX: was p<2 -> staged only half tile
        const int flat = p * 256 + t;
        *(uint4*)&As[flat * 8] = *(const uint4*)&Atile[flat * 8];
        *(uint4*)&Bs[flat * 8] = *(const uint4*)&Btile[flat * 8];
    }
    __syncthreads();

    f32x4 acc[2][2];
#pragma unroll
    for (int i = 0; i < 2; ++i)
#pragma unroll
        for (int j = 0; j < 2; ++j) acc[i][j] = (f32x4)(0.f);

#pragma unroll
    for (int s = 0; s < 4; ++s) {
        bf16x8 a[2], bb[2];
#pragma unroll
        for (int mf = 0; mf < 2; ++mf) {
            const int r = wc * 32 + mf * 16 + l15;
            a[mf] = *(const bf16x8*)&As[r * 128 + swz16(r, s * 4 + lq) * 8];
        }
#pragma unroll
        for (int nf = 0; nf < 2; ++nf) {
            const int pr = wp * 32 + nf * 16 + l15;
            bb[nf] = *(const bf16x8*)&Bs[pr * 128 + swz16(pr, s * 4 + lq) * 8];
        }
#pragma unroll
        for (int mf = 0; mf < 2; ++mf)
#pragma unroll
            for (int nf = 0; nf < 2; ++nf)
                acc[mf][nf] = MFMA16(a[mf], bb[nf], acc[mf][nf]);
    }
    __syncthreads();

    float* Es = (float*)smem;       // [64][66] f32 (16.9 KB), aliases As/Bs
#pragma unroll
    for (int mf = 0; mf < 2; ++mf)
#pragma unroll
        for (int nf = 0; nf < 2; ++nf) {
            const int cl = wc * 32 + mf * 16 + lq * 4;
            const int pl = wp * 32 + nf * 16 + l15;
#pragma unroll
            for (int r = 0; r < 4; ++r)
                Es[(cl + r) * 66 + pl] = acc[mf][nf][r];
        }
    __syncthreads();

    const float rs = rsqrtf(1.f + BNEPS);
#pragma unroll
    for (int p = 0; p < 4; ++p) {
        const int flat = p * 256 + t;
        const int cl = flat >> 4;
        const int p4 = (flat & 15) * 4;
        const int cg = ct * 64 + cl;
        const float beta = bng[cg] * rs * Wb[cg] + bnb[cg];
        const size_t o = ((size_t)b * NC + cg) * HW + pt * 64 + p4;
        const float4 xv = *(const float4*)&xres[o];
        const float4 ev = *(const float4*)&Es[cl * 66 + p4];
        float4 ov;
        ov.x = ev.x + beta + xv.x; ov.y = ev.y + beta + xv.y;
        ov.z = ev.z + beta + xv.z; ov.w = ev.w + beta + xv.w;
        *(float4*)&out[o] = ov;
    }
}

extern "C" void kernel_launch(void* const* d_in, const int* in_sizes, int n_in,
                              void* d_out, int out_size, void* d_ws, size_t ws_size,
                              hipStream_t stream)
{
    const float* x    = (const float*)d_in[0];
    const float* y    = (const float*)d_in[1];
    const float* g_w  = (const float*)d_in[2];
    const float* g_b  = (const float*)d_in[3];
    const float* th_w = (const float*)d_in[4];
    const float* th_b = (const float*)d_in[5];
    const float* ph_w = (const float*)d_in[6];
    const float* ph_b = (const float*)d_in[7];
    const float* Wm   = (const float*)d_in[8];
    const float* Wb   = (const float*)d_in[9];
    const float* bng  = (const float*)d_in[10];
    const float* bnb  = (const float*)d_in[11];
    float* out = (float*)d_out;

    us* TT = (us*)d_ws;                                  // 8*64*8192 us = 8 MB
    us* Pp = TT + (size_t)NB * 64 * 8192;                // 8*4*8192 us = 0.5 MB
    float* gp = (float*)(Pp + (size_t)NB * 4 * 8192);    // 4 MB
    float* pp = gp + (size_t)NB * NI * NP;               // 4 MB
    float* mp = pp + (size_t)NB * NI * NP;               // 16.8 MB
    float* M  = mp + (size_t)NCK * NB * NI * NI;         // 0.5 MB

    const dim3 blk(256);
    k_theta<<<dim3(64, 1, NB), blk, 0, stream>>>(th_w, th_b, x, TT);
    k_gphi<<<dim3(32, 2, NB), blk, 0, stream>>>(g_w, g_b, ph_w, ph_b, y, gp, pp);
    k_mpart<<<dim3(NCK, NB), blk, 0, stream>>>(gp, pp, mp);
    k_msum<<<dim3(128), blk, 0, stream>>>(mp, M);
    k_pgemm<<<dim3(4, NB), blk, 0, stream>>>(M, Wm, bng, Pp);
    k_final<<<dim3(64, 4, NB), blk, 0, stream>>>(Pp, TT, Wb, bng, bnb, x, out);
}